// Round 1
// baseline (632.256 us; speedup 1.0000x reference)
//
#include <hip/hip_runtime.h>
#include <math.h>

#define B 128
#define H 2048
#define S 512
#define FOURH 8192

// ---------------------------------------------------------------------------
// Kernel 1: gates = embed[tw] @ W_ih^T + b_ih + hx @ W_hh^T + b_hh
// Tiled f32 GEMM: M=128 (batch), N=8192 (4H), K=2048 twice (two phases).
// 64x64 tile, 256 threads, each thread computes 4x4 outputs, BK=16.
// ---------------------------------------------------------------------------
__global__ __launch_bounds__(256) void gates_gemm(
    const int* __restrict__ tw,
    const float* __restrict__ embed,
    const float* __restrict__ hx,
    const float* __restrict__ W_ih,
    const float* __restrict__ W_hh,
    const float* __restrict__ b_ih,
    const float* __restrict__ b_hh,
    float* __restrict__ gates)
{
    __shared__ float As[16][64];
    __shared__ float Bs[16][64];
    const int tid = threadIdx.x;
    const int tx = tid & 15, ty = tid >> 4;
    const int n0 = blockIdx.x * 64;   // j tile (over 4H)
    const int m0 = blockIdx.y * 64;   // b tile

    const int lrow = tid >> 2;        // 0..63 (row within tile for loading)
    const int lk4  = (tid & 3) * 4;   // 0,4,8,12 (k offset within BK)

    const int b_idx = m0 + lrow;
    const size_t embed_row = (size_t)tw[b_idx] * H;

    float acc[4][4] = {};

    for (int phase = 0; phase < 2; ++phase) {
        const float* Asrc = (phase == 0) ? (embed + embed_row)
                                         : (hx + (size_t)b_idx * H);
        const float* Wsrc = (phase == 0) ? W_ih : W_hh;
        const float* Brow = Wsrc + (size_t)(n0 + lrow) * H;

        for (int k0 = 0; k0 < H; k0 += 16) {
            float4 av = *(const float4*)(Asrc + k0 + lk4);
            float4 bv = *(const float4*)(Brow + k0 + lk4);
            __syncthreads();
            As[lk4+0][lrow] = av.x; As[lk4+1][lrow] = av.y;
            As[lk4+2][lrow] = av.z; As[lk4+3][lrow] = av.w;
            Bs[lk4+0][lrow] = bv.x; Bs[lk4+1][lrow] = bv.y;
            Bs[lk4+2][lrow] = bv.z; Bs[lk4+3][lrow] = bv.w;
            __syncthreads();
            #pragma unroll
            for (int kk = 0; kk < 16; ++kk) {
                float a[4], bb[4];
                #pragma unroll
                for (int i = 0; i < 4; ++i) a[i]  = As[kk][ty*4+i];
                #pragma unroll
                for (int i = 0; i < 4; ++i) bb[i] = Bs[kk][tx*4+i];
                #pragma unroll
                for (int i = 0; i < 4; ++i)
                    #pragma unroll
                    for (int j = 0; j < 4; ++j)
                        acc[i][j] = fmaf(a[i], bb[j], acc[i][j]);
            }
        }
    }

    #pragma unroll
    for (int i = 0; i < 4; ++i) {
        const int b = m0 + ty*4 + i;
        #pragma unroll
        for (int j = 0; j < 4; ++j) {
            const int n = n0 + tx*4 + j;
            gates[(size_t)b * FOURH + n] = acc[i][j] + b_ih[n] + b_hh[n];
        }
    }
}

// ---------------------------------------------------------------------------
// Kernel 2: LSTM cell elementwise (PyTorch gate order i,f,g,o)
// ---------------------------------------------------------------------------
__global__ __launch_bounds__(256) void lstm_cell(
    const float* __restrict__ gates,
    const float* __restrict__ cx,
    float* __restrict__ hx_new)
{
    const int idx = blockIdx.x * 256 + threadIdx.x;   // over B*H
    const int b = idx / H, h = idx % H;
    const float* g0 = gates + (size_t)b * FOURH;
    float gi = g0[h];
    float gf = g0[H + h];
    float gg = g0[2*H + h];
    float go = g0[3*H + h];
    gi = 1.f / (1.f + expf(-gi));
    gf = 1.f / (1.f + expf(-gf));
    go = 1.f / (1.f + expf(-go));
    gg = tanhf(gg);
    float c = gf * cx[idx] + gi * gg;
    hx_new[idx] = go * tanhf(c);
}

// ---------------------------------------------------------------------------
// Kernel 3: masked scores[s][b] = sum_h hx_new[b][h] * ew[s][b][h]
// One wave (64 lanes) per (s,b) pair; 4 waves per block.
// ---------------------------------------------------------------------------
__global__ __launch_bounds__(256) void score_kernel(
    const float* __restrict__ hx_new,
    const float* __restrict__ ew,
    const int* __restrict__ mask,
    float* __restrict__ scores)
{
    const int w    = blockIdx.x * 4 + (threadIdx.x >> 6);
    const int lane = threadIdx.x & 63;
    const int b = w & (B - 1);
    const int s = w >> 7;                    // w / B
    const float* ewp = ew + ((size_t)s * B + b) * H;
    const float* hp  = hx_new + (size_t)b * H;
    float sum = 0.f;
    #pragma unroll
    for (int it = 0; it < H / 256; ++it) {   // 8 iterations
        const int h = it * 256 + lane * 4;
        float4 e = *(const float4*)(ewp + h);
        float4 x = *(const float4*)(hp + h);
        sum += e.x*x.x + e.y*x.y + e.z*x.z + e.w*x.w;
    }
    #pragma unroll
    for (int off = 32; off; off >>= 1) sum += __shfl_down(sum, off, 64);
    if (lane == 0) {
        scores[s * B + b] = (mask[s * B + b] == 0) ? -1e9f : sum;
    }
}

// ---------------------------------------------------------------------------
// Kernel 4: softmax over s (axis 0) per batch column b
// ---------------------------------------------------------------------------
__global__ __launch_bounds__(256) void softmax_kernel(
    const float* __restrict__ scores,
    float* __restrict__ align)
{
    __shared__ float red[256];
    const int b = blockIdx.x;
    const int tid = threadIdx.x;
    float v0 = scores[tid * B + b];
    float v1 = scores[(tid + 256) * B + b];
    red[tid] = fmaxf(v0, v1);
    __syncthreads();
    for (int st = 128; st; st >>= 1) {
        if (tid < st) red[tid] = fmaxf(red[tid], red[tid + st]);
        __syncthreads();
    }
    const float mx = red[0];
    __syncthreads();
    float e0 = expf(v0 - mx), e1 = expf(v1 - mx);
    red[tid] = e0 + e1;
    __syncthreads();
    for (int st = 128; st; st >>= 1) {
        if (tid < st) red[tid] += red[tid + st];
        __syncthreads();
    }
    const float inv = 1.f / red[0];
    align[tid * B + b]         = e0 * inv;
    align[(tid + 256) * B + b] = e1 * inv;
}

// ---------------------------------------------------------------------------
// Kernel 5: content[b][h] = sum_s align[s][b] * ew[s][b][h]
// One block per (b, half-of-H); 256 threads x float4 = 1024 floats per block.
// ---------------------------------------------------------------------------
__global__ __launch_bounds__(256) void content_kernel(
    const float* __restrict__ align,
    const float* __restrict__ ew,
    float* __restrict__ content)
{
    __shared__ float al[S];
    const int b    = blockIdx.x >> 1;
    const int half = blockIdx.x & 1;
    const int tid  = threadIdx.x;
    for (int s = tid; s < S; s += 256) al[s] = align[s * B + b];
    __syncthreads();
    const int h0 = half * 1024 + tid * 4;
    float4 acc = {0.f, 0.f, 0.f, 0.f};
    const float* base = ew + (size_t)b * H + h0;
    for (int s = 0; s < S; ++s) {
        float4 v = *(const float4*)(base + (size_t)s * B * H);
        const float a = al[s];
        acc.x = fmaf(a, v.x, acc.x);
        acc.y = fmaf(a, v.y, acc.y);
        acc.z = fmaf(a, v.z, acc.z);
        acc.w = fmaf(a, v.w, acc.w);
    }
    *(float4*)(content + (size_t)b * H + h0) = acc;
}

// ---------------------------------------------------------------------------
// Kernel 6: out = tanh(concat(content,hx_new) @ attn_W^T + attn_b)
// Tiled f32 GEMM: M=128, N=2048, K=4096 (two phases of 2048).
// ---------------------------------------------------------------------------
__global__ __launch_bounds__(256) void attn_gemm(
    const float* __restrict__ content,
    const float* __restrict__ hx_new,
    const float* __restrict__ attn_W,
    const float* __restrict__ attn_b,
    float* __restrict__ out)
{
    __shared__ float As[16][64];
    __shared__ float Bs[16][64];
    const int tid = threadIdx.x;
    const int tx = tid & 15, ty = tid >> 4;
    const int n0 = blockIdx.x * 64;   // j tile (over H)
    const int m0 = blockIdx.y * 64;   // b tile

    const int lrow = tid >> 2;
    const int lk4  = (tid & 3) * 4;
    const int b_idx = m0 + lrow;

    float acc[4][4] = {};

    for (int phase = 0; phase < 2; ++phase) {
        const float* Asrc = ((phase == 0) ? content : hx_new) + (size_t)b_idx * H;
        const float* Brow = attn_W + (size_t)(n0 + lrow) * (2 * H) + phase * H;

        for (int k0 = 0; k0 < H; k0 += 16) {
            float4 av = *(const float4*)(Asrc + k0 + lk4);
            float4 bv = *(const float4*)(Brow + k0 + lk4);
            __syncthreads();
            As[lk4+0][lrow] = av.x; As[lk4+1][lrow] = av.y;
            As[lk4+2][lrow] = av.z; As[lk4+3][lrow] = av.w;
            Bs[lk4+0][lrow] = bv.x; Bs[lk4+1][lrow] = bv.y;
            Bs[lk4+2][lrow] = bv.z; Bs[lk4+3][lrow] = bv.w;
            __syncthreads();
            #pragma unroll
            for (int kk = 0; kk < 16; ++kk) {
                float a[4], bb[4];
                #pragma unroll
                for (int i = 0; i < 4; ++i) a[i]  = As[kk][ty*4+i];
                #pragma unroll
                for (int i = 0; i < 4; ++i) bb[i] = Bs[kk][tx*4+i];
                #pragma unroll
                for (int i = 0; i < 4; ++i)
                    #pragma unroll
                    for (int j = 0; j < 4; ++j)
                        acc[i][j] = fmaf(a[i], bb[j], acc[i][j]);
            }
        }
    }

    #pragma unroll
    for (int i = 0; i < 4; ++i) {
        const int b = m0 + ty*4 + i;
        #pragma unroll
        for (int j = 0; j < 4; ++j) {
            const int n = n0 + tx*4 + j;
            out[(size_t)b * H + n] = tanhf(acc[i][j] + attn_b[n]);
        }
    }
}

// ---------------------------------------------------------------------------
extern "C" void kernel_launch(void* const* d_in, const int* in_sizes, int n_in,
                              void* d_out, int out_size, void* d_ws, size_t ws_size,
                              hipStream_t stream)
{
    const int*   tw     = (const int*)d_in[0];
    const float* hx     = (const float*)d_in[1];
    const float* cx     = (const float*)d_in[2];
    const float* ew     = (const float*)d_in[3];
    const int*   mask   = (const int*)d_in[4];
    const float* embed  = (const float*)d_in[5];
    const float* W_ih   = (const float*)d_in[6];
    const float* W_hh   = (const float*)d_in[7];
    const float* b_ih   = (const float*)d_in[8];
    const float* b_hh   = (const float*)d_in[9];
    const float* attn_W = (const float*)d_in[10];
    const float* attn_b = (const float*)d_in[11];
    float* out = (float*)d_out;

    float* ws      = (float*)d_ws;
    float* gates   = ws;                                // B*4H = 1048576
    float* hx_new  = gates  + (size_t)B * FOURH;        // B*H  = 262144
    float* scores  = hx_new + (size_t)B * H;            // S*B  = 65536
    float* align   = scores + (size_t)S * B;            // S*B  = 65536
    float* content = align  + (size_t)S * B;            // B*H  = 262144

    gates_gemm<<<dim3(FOURH/64, B/64), 256, 0, stream>>>(
        tw, embed, hx, W_ih, W_hh, b_ih, b_hh, gates);
    lstm_cell<<<(B*H)/256, 256, 0, stream>>>(gates, cx, hx_new);
    score_kernel<<<(S*B)/4, 256, 0, stream>>>(hx_new, ew, mask, scores);
    softmax_kernel<<<B, 256, 0, stream>>>(scores, align);
    content_kernel<<<B*2, 256, 0, stream>>>(align, ew, content);
    attn_gemm<<<dim3(H/64, B/64), 256, 0, stream>>>(
        content, hx_new, attn_W, attn_b, out);
}

// Round 2
// 363.225 us; speedup vs baseline: 1.7407x; 1.7407x over previous
//
#include <hip/hip_runtime.h>
#include <math.h>

#define B 128
#define H 2048
#define S 512
#define FOURH 8192

typedef float  f32x4  __attribute__((ext_vector_type(4)));
typedef short  bf16x8 __attribute__((ext_vector_type(8)));
typedef unsigned short u16;
typedef unsigned short u16x8 __attribute__((ext_vector_type(8)));
typedef unsigned short u16x4 __attribute__((ext_vector_type(4)));

// Split f32 -> bf16 hi + bf16 lo (truncation; lo captures residual, total ~2^-16)
__device__ __forceinline__ void cvt_hilo(float x, u16& h, u16& lo) {
    unsigned int u = __float_as_uint(x);
    h = (u16)(u >> 16);
    float hf = __uint_as_float(u & 0xFFFF0000u);
    float r = x - hf;
    lo = (u16)(__float_as_uint(r) >> 16);
}

// ---------------------------------------------------------------------------
// Kernel 1: build A0 = [embed[tw] | hx] as bf16 hi/lo pair [128][4096]
// ---------------------------------------------------------------------------
__global__ __launch_bounds__(256) void gather_convert_A0(
    const int* __restrict__ tw,
    const float* __restrict__ embed,
    const float* __restrict__ hx,
    u16* __restrict__ Ah, u16* __restrict__ Al)
{
    const int i = (blockIdx.x * 256 + threadIdx.x) * 8;   // over 128*4096
    const int b = i >> 12;
    const int col = i & 4095;
    const float* src = (col < H) ? (embed + (size_t)tw[b] * H + col)
                                 : (hx + (size_t)b * H + (col - H));
    f32x4 v0 = *(const f32x4*)(src);
    f32x4 v1 = *(const f32x4*)(src + 4);
    u16x8 hv, lv;
    #pragma unroll
    for (int j = 0; j < 4; ++j) { u16 h, l; cvt_hilo(v0[j], h, l); hv[j] = h; lv[j] = l; }
    #pragma unroll
    for (int j = 0; j < 4; ++j) { u16 h, l; cvt_hilo(v1[j], h, l); hv[4+j] = h; lv[4+j] = l; }
    *(u16x8*)(Ah + i) = hv;
    *(u16x8*)(Al + i) = lv;
}

// ---------------------------------------------------------------------------
// Kernel: convert cat f32 [128][4096] -> bf16 hi/lo
// ---------------------------------------------------------------------------
__global__ __launch_bounds__(256) void convert_cat(
    const float* __restrict__ cat, u16* __restrict__ Ah, u16* __restrict__ Al)
{
    const int i = (blockIdx.x * 256 + threadIdx.x) * 8;
    f32x4 v0 = *(const f32x4*)(cat + i);
    f32x4 v1 = *(const f32x4*)(cat + i + 4);
    u16x8 hv, lv;
    #pragma unroll
    for (int j = 0; j < 4; ++j) { u16 h, l; cvt_hilo(v0[j], h, l); hv[j] = h; lv[j] = l; }
    #pragma unroll
    for (int j = 0; j < 4; ++j) { u16 h, l; cvt_hilo(v1[j], h, l); hv[4+j] = h; lv[4+j] = l; }
    *(u16x8*)(Ah + i) = hv;
    *(u16x8*)(Al + i) = lv;
}

// ---------------------------------------------------------------------------
// Split-bf16 MFMA GEMM: out[128][NOUT] = A[128][4096] @ W^T (+bias epilogue)
// BM=128, BN=32, BK=32, 256 threads (4 waves), wave w owns rows w*32..w*32+31.
// 3 MFMA products per tile: Ah*Wh + Ah*Wl + Al*Wh  (err ~2^-16).
// MODE 0: W = [W_ih | W_hh] rows (k<2048 -> W0, else W1); out = gates + b_ih + b_hh
// MODE 1: W = attn_W [N][4096]; out = tanh(acc + attn_b)
// ---------------------------------------------------------------------------
template<int MODE>
__global__ __launch_bounds__(256) void split_gemm(
    const u16* __restrict__ Ah, const u16* __restrict__ Al,
    const float* __restrict__ W0, const float* __restrict__ W1,
    const float* __restrict__ bias0, const float* __restrict__ bias1,
    float* __restrict__ out)
{
    constexpr int NOUT = (MODE == 0) ? FOURH : H;
    __shared__ u16 AhS[128][40];
    __shared__ u16 AlS[128][40];
    __shared__ u16 BhS[32][40];
    __shared__ u16 BlS[32][40];

    const int tid = threadIdx.x;
    const int n0 = blockIdx.x * 32;
    // A staging: thread -> (row, 16-col half)
    const int ar = tid >> 1;
    const int ac = (tid & 1) * 16;
    // B staging: thread -> (row, 4-col quarter)
    const int br = tid >> 3;
    const int bc = (tid & 7) * 4;
    // fragment coords
    const int wv = tid >> 6;
    const int lane = tid & 63;
    const int frow = lane & 15;
    const int fk = (lane >> 4) * 8;
    const int crow = (lane >> 4) * 4;

    f32x4 acc[2][2];
    #pragma unroll
    for (int mi = 0; mi < 2; ++mi)
        #pragma unroll
        for (int ni = 0; ni < 2; ++ni)
            acc[mi][ni] = (f32x4){0.f, 0.f, 0.f, 0.f};

    u16x8 rah0, rah1, ral0, ral1;
    f32x4 rbv;

    auto load_tile = [&](int k0) {
        const u16* ap = Ah + (size_t)ar * 4096 + k0 + ac;
        const u16* lp = Al + (size_t)ar * 4096 + k0 + ac;
        rah0 = *(const u16x8*)(ap);
        rah1 = *(const u16x8*)(ap + 8);
        ral0 = *(const u16x8*)(lp);
        ral1 = *(const u16x8*)(lp + 8);
        const float* wp;
        if (MODE == 0)
            wp = (k0 < H) ? (W0 + (size_t)(n0 + br) * H + k0 + bc)
                          : (W1 + (size_t)(n0 + br) * H + (k0 - H) + bc);
        else
            wp = W0 + (size_t)(n0 + br) * (2 * H) + k0 + bc;
        rbv = *(const f32x4*)(wp);
    };

    load_tile(0);

    for (int ks = 0; ks < 4096 / 32; ++ks) {
        __syncthreads();
        *(u16x8*)&AhS[ar][ac]     = rah0;
        *(u16x8*)&AhS[ar][ac + 8] = rah1;
        *(u16x8*)&AlS[ar][ac]     = ral0;
        *(u16x8*)&AlS[ar][ac + 8] = ral1;
        u16x4 bh, bl;
        #pragma unroll
        for (int j = 0; j < 4; ++j) { u16 h, l; cvt_hilo(rbv[j], h, l); bh[j] = h; bl[j] = l; }
        *(u16x4*)&BhS[br][bc] = bh;
        *(u16x4*)&BlS[br][bc] = bl;
        __syncthreads();
        if (ks + 1 < 4096 / 32) load_tile((ks + 1) * 32);

        bf16x8 a_h[2], a_l[2], b_h[2], b_l[2];
        #pragma unroll
        for (int mi = 0; mi < 2; ++mi) {
            a_h[mi] = *(const bf16x8*)&AhS[wv * 32 + mi * 16 + frow][fk];
            a_l[mi] = *(const bf16x8*)&AlS[wv * 32 + mi * 16 + frow][fk];
        }
        #pragma unroll
        for (int ni = 0; ni < 2; ++ni) {
            b_h[ni] = *(const bf16x8*)&BhS[ni * 16 + frow][fk];
            b_l[ni] = *(const bf16x8*)&BlS[ni * 16 + frow][fk];
        }
        #pragma unroll
        for (int mi = 0; mi < 2; ++mi)
            #pragma unroll
            for (int ni = 0; ni < 2; ++ni) {
                acc[mi][ni] = __builtin_amdgcn_mfma_f32_16x16x32_bf16(a_h[mi], b_h[ni], acc[mi][ni], 0, 0, 0);
                acc[mi][ni] = __builtin_amdgcn_mfma_f32_16x16x32_bf16(a_h[mi], b_l[ni], acc[mi][ni], 0, 0, 0);
                acc[mi][ni] = __builtin_amdgcn_mfma_f32_16x16x32_bf16(a_l[mi], b_h[ni], acc[mi][ni], 0, 0, 0);
            }
    }

    // epilogue: C/D layout col=lane&15, row=(lane>>4)*4+j  [m89/m91]
    #pragma unroll
    for (int mi = 0; mi < 2; ++mi)
        #pragma unroll
        for (int ni = 0; ni < 2; ++ni) {
            const int col = n0 + ni * 16 + frow;
            const float b0v = bias0[col];
            const float b1v = (MODE == 0) ? bias1[col] : 0.f;
            #pragma unroll
            for (int j = 0; j < 4; ++j) {
                const int row = wv * 32 + mi * 16 + crow + j;
                const float v = acc[mi][ni][j];
                if (MODE == 0)
                    out[(size_t)row * FOURH + col] = v + b0v + b1v;
                else
                    out[(size_t)row * H + col] = tanhf(v + b0v);
            }
        }
}

// ---------------------------------------------------------------------------
// LSTM cell elementwise; writes hx_new into cat[:, 2048:]
// ---------------------------------------------------------------------------
__global__ __launch_bounds__(256) void lstm_cell(
    const float* __restrict__ gates,
    const float* __restrict__ cx,
    float* __restrict__ cat)
{
    const int idx = blockIdx.x * 256 + threadIdx.x;   // over B*H
    const int b = idx >> 11, h = idx & (H - 1);
    const float* g0 = gates + (size_t)b * FOURH;
    float gi = g0[h];
    float gf = g0[H + h];
    float gg = g0[2 * H + h];
    float go = g0[3 * H + h];
    gi = 1.f / (1.f + expf(-gi));
    gf = 1.f / (1.f + expf(-gf));
    go = 1.f / (1.f + expf(-go));
    gg = tanhf(gg);
    float c = gf * cx[idx] + gi * gg;
    cat[(size_t)b * 4096 + H + h] = go * tanhf(c);
}

// ---------------------------------------------------------------------------
// Fused attention: one pass over ew, online softmax (flash-style).
// Grid: 512 blocks = 128 b x 4 chunks of 128 s. 4 waves/block, wave w owns
// s = chunk*128 + w*32 .. +32 (full 2048-dot is wave-local: 64 lanes x 32 f32).
// Block merges 4 wave-partials; writes unnormalized o_part + (M, L).
// ---------------------------------------------------------------------------
__global__ __launch_bounds__(256) void fused_attn(
    const float* __restrict__ cat,     // hx_new at cat[:, 2048:]
    const float* __restrict__ ew,      // [512][128][2048]
    const int* __restrict__ mask,      // [512][128]
    float* __restrict__ o_part,        // [128][4][2048] unnormalized
    float* __restrict__ ml_part)       // [128][4][2] = (M, L)
{
    __shared__ float mlbuf[4][2];
    __shared__ float obuf[4][2048];

    const int tid = threadIdx.x;
    const int b = blockIdx.x >> 2;
    const int c = blockIdx.x & 3;
    const int wv = tid >> 6;
    const int lane = tid & 63;
    const int s0 = c * 128 + wv * 32;

    // hx_new fragment: lane covers h = j*256 + lane*4 + t
    f32x4 hxv[8];
    const float* hp = cat + (size_t)b * 4096 + H + lane * 4;
    #pragma unroll
    for (int j = 0; j < 8; ++j) hxv[j] = *(const f32x4*)(hp + j * 256);

    f32x4 o4[8];
    #pragma unroll
    for (int j = 0; j < 8; ++j) o4[j] = (f32x4){0.f, 0.f, 0.f, 0.f};
    float m = -3.0e38f, l = 0.f;

    const size_t SSTRIDE = (size_t)B * H;
    const float* rowp = ew + ((size_t)s0 * B + b) * H + lane * 4;

    f32x4 ev[8];
    #pragma unroll
    for (int j = 0; j < 8; ++j) ev[j] = *(const f32x4*)(rowp + j * 256);

    for (int si = 0; si < 32; ++si) {
        f32x4 cur[8];
        #pragma unroll
        for (int j = 0; j < 8; ++j) cur[j] = ev[j];
        if (si < 31) {
            const float* np = rowp + (size_t)(si + 1) * SSTRIDE;
            #pragma unroll
            for (int j = 0; j < 8; ++j) ev[j] = *(const f32x4*)(np + j * 256);
        }
        // dot over h
        float p = 0.f;
        #pragma unroll
        for (int j = 0; j < 8; ++j) {
            f32x4 t = cur[j] * hxv[j];
            p += t[0] + t[1] + t[2] + t[3];
        }
        #pragma unroll
        for (int off = 32; off; off >>= 1) p += __shfl_xor(p, off, 64);
        // mask + online softmax update (uniform across wave)
        if (mask[(s0 + si) * B + b] == 0) p = -1e9f;
        const float mn = fmaxf(m, p);
        const float sc = expf(m - mn);
        const float pe = expf(p - mn);
        l = l * sc + pe;
        #pragma unroll
        for (int j = 0; j < 8; ++j) o4[j] = o4[j] * sc + cur[j] * pe;
        m = mn;
    }

    // block merge of 4 wave-partials
    if (lane == 0) { mlbuf[wv][0] = m; mlbuf[wv][1] = l; }
    __syncthreads();
    const float M = fmaxf(fmaxf(mlbuf[0][0], mlbuf[1][0]), fmaxf(mlbuf[2][0], mlbuf[3][0]));
    const float wsc = expf(m - M);
    float L = 0.f;
    #pragma unroll
    for (int w = 0; w < 4; ++w) L += mlbuf[w][1] * expf(mlbuf[w][0] - M);
    #pragma unroll
    for (int j = 0; j < 8; ++j)
        *(f32x4*)&obuf[wv][j * 256 + lane * 4] = o4[j] * wsc;
    __syncthreads();

    const int h0 = tid * 8;
    f32x4 s0v = (f32x4){0.f, 0.f, 0.f, 0.f}, s1v = s0v;
    #pragma unroll
    for (int w = 0; w < 4; ++w) {
        s0v += *(const f32x4*)&obuf[w][h0];
        s1v += *(const f32x4*)&obuf[w][h0 + 4];
    }
    float* op = o_part + ((size_t)b * 4 + c) * H + h0;
    *(f32x4*)(op)     = s0v;
    *(f32x4*)(op + 4) = s1v;
    if (tid == 0) {
        ml_part[((size_t)b * 4 + c) * 2]     = M;
        ml_part[((size_t)b * 4 + c) * 2 + 1] = L;
    }
}

// ---------------------------------------------------------------------------
// Combine 4 chunk-partials per b -> content, written into cat[:, 0:2048]
// ---------------------------------------------------------------------------
__global__ __launch_bounds__(256) void attn_combine(
    const float* __restrict__ o_part,
    const float* __restrict__ ml_part,
    float* __restrict__ cat)
{
    const int b = blockIdx.x;
    const int tid = threadIdx.x;
    float Mc[4], Lc[4];
    #pragma unroll
    for (int c = 0; c < 4; ++c) {
        Mc[c] = ml_part[((size_t)b * 4 + c) * 2];
        Lc[c] = ml_part[((size_t)b * 4 + c) * 2 + 1];
    }
    const float Mg = fmaxf(fmaxf(Mc[0], Mc[1]), fmaxf(Mc[2], Mc[3]));
    float Lg = 0.f;
    #pragma unroll
    for (int c = 0; c < 4; ++c) Lg += Lc[c] * expf(Mc[c] - Mg);
    const float inv = 1.f / Lg;
    const int h0 = tid * 8;
    f32x4 a0 = (f32x4){0.f, 0.f, 0.f, 0.f}, a1 = a0;
    #pragma unroll
    for (int c = 0; c < 4; ++c) {
        const float scl = expf(Mc[c] - Mg) * inv;
        const float* op = o_part + ((size_t)b * 4 + c) * H + h0;
        a0 += *(const f32x4*)(op) * scl;
        a1 += *(const f32x4*)(op + 4) * scl;
    }
    float* cp = cat + (size_t)b * 4096 + h0;
    *(f32x4*)(cp)     = a0;
    *(f32x4*)(cp + 4) = a1;
}

// ---------------------------------------------------------------------------
extern "C" void kernel_launch(void* const* d_in, const int* in_sizes, int n_in,
                              void* d_out, int out_size, void* d_ws, size_t ws_size,
                              hipStream_t stream)
{
    const int*   tw     = (const int*)d_in[0];
    const float* hx     = (const float*)d_in[1];
    const float* cx     = (const float*)d_in[2];
    const float* ew     = (const float*)d_in[3];
    const int*   mask   = (const int*)d_in[4];
    const float* embed  = (const float*)d_in[5];
    const float* W_ih   = (const float*)d_in[6];
    const float* W_hh   = (const float*)d_in[7];
    const float* b_ih   = (const float*)d_in[8];
    const float* b_hh   = (const float*)d_in[9];
    const float* attn_W = (const float*)d_in[10];
    const float* attn_b = (const float*)d_in[11];
    float* out = (float*)d_out;

    float* ws     = (float*)d_ws;
    float* gates  = ws;                         // 128*8192
    float* cat    = gates + (size_t)B * FOURH;  // 128*4096
    float* o_part = cat + (size_t)B * 4096;     // 128*4*2048
    float* ml     = o_part + (size_t)B * 4 * H; // 128*4*2
    u16* Ah0 = (u16*)(ml + 1024);
    u16* Al0 = Ah0 + (size_t)B * 4096;
    u16* Ah1 = Al0 + (size_t)B * 4096;
    u16* Al1 = Ah1 + (size_t)B * 4096;

    gather_convert_A0<<<256, 256, 0, stream>>>(tw, embed, hx, Ah0, Al0);
    split_gemm<0><<<FOURH / 32, 256, 0, stream>>>(Ah0, Al0, W_ih, W_hh, b_ih, b_hh, gates);
    lstm_cell<<<(B * H) / 256, 256, 0, stream>>>(gates, cx, cat);
    fused_attn<<<B * 4, 256, 0, stream>>>(cat, ew, mask, o_part, ml);
    attn_combine<<<B, 256, 0, stream>>>(o_part, ml, cat);
    convert_cat<<<256, 256, 0, stream>>>(cat, Ah1, Al1);
    split_gemm<1><<<H / 32, 256, 0, stream>>>(Ah1, Al1, attn_W, attn_W, attn_b, attn_b, out);
}

// Round 3
// 230.782 us; speedup vs baseline: 2.7396x; 1.5739x over previous
//
#include <hip/hip_runtime.h>
#include <math.h>

#define B 128
#define H 2048
#define S 512
#define FOURH 8192

typedef float  f32x4  __attribute__((ext_vector_type(4)));
typedef short  bf16x8 __attribute__((ext_vector_type(8)));
typedef unsigned short u16;
typedef unsigned short u16x8 __attribute__((ext_vector_type(8)));
typedef unsigned short u16x4 __attribute__((ext_vector_type(4)));

// Split f32 -> bf16 hi + bf16 lo (truncation; lo captures residual, total ~2^-16)
__device__ __forceinline__ void cvt_hilo(float x, u16& h, u16& lo) {
    unsigned int u = __float_as_uint(x);
    h = (u16)(u >> 16);
    float hf = __uint_as_float(u & 0xFFFF0000u);
    float r = x - hf;
    lo = (u16)(__float_as_uint(r) >> 16);
}

// ---------------------------------------------------------------------------
// Kernel 1: build A0 = [embed[tw] | hx] as bf16 hi/lo pair [128][4096]
// ---------------------------------------------------------------------------
__global__ __launch_bounds__(256) void gather_convert_A0(
    const int* __restrict__ tw,
    const float* __restrict__ embed,
    const float* __restrict__ hx,
    u16* __restrict__ Ah, u16* __restrict__ Al)
{
    const int i = (blockIdx.x * 256 + threadIdx.x) * 8;   // over 128*4096
    const int b = i >> 12;
    const int col = i & 4095;
    const float* src = (col < H) ? (embed + (size_t)tw[b] * H + col)
                                 : (hx + (size_t)b * H + (col - H));
    f32x4 v0 = *(const f32x4*)(src);
    f32x4 v1 = *(const f32x4*)(src + 4);
    u16x8 hv, lv;
    #pragma unroll
    for (int j = 0; j < 4; ++j) { u16 h, l; cvt_hilo(v0[j], h, l); hv[j] = h; lv[j] = l; }
    #pragma unroll
    for (int j = 0; j < 4; ++j) { u16 h, l; cvt_hilo(v1[j], h, l); hv[4+j] = h; lv[4+j] = l; }
    *(u16x8*)(Ah + i) = hv;
    *(u16x8*)(Al + i) = lv;
}

// ---------------------------------------------------------------------------
// Split-bf16 MFMA GEMM with split-K (partials; no bias/activation here).
// BM=128, BN=32, BK=32, 256 threads (4 waves), wave w owns rows w*32..+31.
// 3 MFMA per tile pair: Ah*Wh + Ah*Wl + Al*Wh (err ~2^-16).
// MODE 0: K=4096 split 2 (slice == W_ih / W_hh); out [2][128][8192]
// MODE 1: K=4096 split 4 over attn_W [2048][4096]; out [4][128][2048]
// ---------------------------------------------------------------------------
template<int MODE>
__global__ __launch_bounds__(256) void split_gemm(
    const u16* __restrict__ Ah, const u16* __restrict__ Al,
    const float* __restrict__ W0, const float* __restrict__ W1,
    float* __restrict__ outp)
{
    constexpr int NOUT = (MODE == 0) ? FOURH : H;
    constexpr int KLEN = (MODE == 0) ? 2048 : 1024;
    __shared__ u16 AhS[128][40];
    __shared__ u16 AlS[128][40];
    __shared__ u16 BhS[32][40];
    __shared__ u16 BlS[32][40];

    const int tid = threadIdx.x;
    const int n0 = blockIdx.x * 32;
    const int kz = blockIdx.y;
    const int kbase = kz * KLEN;
    const int ar = tid >> 1, ac = (tid & 1) * 16;
    const int br = tid >> 3, bc = (tid & 7) * 4;
    const int wv = tid >> 6, lane = tid & 63;
    const int frow = lane & 15, fk = (lane >> 4) * 8, crow = (lane >> 4) * 4;

    const float* Wrow;
    if (MODE == 0)
        Wrow = ((kz == 0) ? W0 : W1) + (size_t)(n0 + br) * H;
    else
        Wrow = W0 + (size_t)(n0 + br) * (2 * H) + kbase;

    const u16* Abase = Ah + (size_t)ar * 4096 + kbase + ac;
    const u16* Lbase = Al + (size_t)ar * 4096 + kbase + ac;

    f32x4 acc[2][2];
    #pragma unroll
    for (int mi = 0; mi < 2; ++mi)
        #pragma unroll
        for (int ni = 0; ni < 2; ++ni)
            acc[mi][ni] = (f32x4){0.f, 0.f, 0.f, 0.f};

    u16x8 rah0, rah1, ral0, ral1;
    f32x4 rbv;
    auto load_tile = [&](int k0) {
        rah0 = *(const u16x8*)(Abase + k0);
        rah1 = *(const u16x8*)(Abase + k0 + 8);
        ral0 = *(const u16x8*)(Lbase + k0);
        ral1 = *(const u16x8*)(Lbase + k0 + 8);
        rbv  = *(const f32x4*)(Wrow + k0 + bc);
    };

    load_tile(0);

    for (int ks = 0; ks < KLEN / 32; ++ks) {
        __syncthreads();
        *(u16x8*)&AhS[ar][ac]     = rah0;
        *(u16x8*)&AhS[ar][ac + 8] = rah1;
        *(u16x8*)&AlS[ar][ac]     = ral0;
        *(u16x8*)&AlS[ar][ac + 8] = ral1;
        u16x4 bh, bl;
        #pragma unroll
        for (int j = 0; j < 4; ++j) { u16 h, l; cvt_hilo(rbv[j], h, l); bh[j] = h; bl[j] = l; }
        *(u16x4*)&BhS[br][bc] = bh;
        *(u16x4*)&BlS[br][bc] = bl;
        __syncthreads();
        if (ks + 1 < KLEN / 32) load_tile((ks + 1) * 32);

        bf16x8 a_h[2], a_l[2], b_h[2], b_l[2];
        #pragma unroll
        for (int mi = 0; mi < 2; ++mi) {
            a_h[mi] = *(const bf16x8*)&AhS[wv * 32 + mi * 16 + frow][fk];
            a_l[mi] = *(const bf16x8*)&AlS[wv * 32 + mi * 16 + frow][fk];
        }
        #pragma unroll
        for (int ni = 0; ni < 2; ++ni) {
            b_h[ni] = *(const bf16x8*)&BhS[ni * 16 + frow][fk];
            b_l[ni] = *(const bf16x8*)&BlS[ni * 16 + frow][fk];
        }
        #pragma unroll
        for (int mi = 0; mi < 2; ++mi)
            #pragma unroll
            for (int ni = 0; ni < 2; ++ni) {
                acc[mi][ni] = __builtin_amdgcn_mfma_f32_16x16x32_bf16(a_h[mi], b_h[ni], acc[mi][ni], 0, 0, 0);
                acc[mi][ni] = __builtin_amdgcn_mfma_f32_16x16x32_bf16(a_h[mi], b_l[ni], acc[mi][ni], 0, 0, 0);
                acc[mi][ni] = __builtin_amdgcn_mfma_f32_16x16x32_bf16(a_l[mi], b_h[ni], acc[mi][ni], 0, 0, 0);
            }
    }

    // C/D layout: col=lane&15, row=(lane>>4)*4+j  [m89/m91]
    #pragma unroll
    for (int mi = 0; mi < 2; ++mi)
        #pragma unroll
        for (int ni = 0; ni < 2; ++ni) {
            const int col = n0 + ni * 16 + frow;
            #pragma unroll
            for (int j = 0; j < 4; ++j) {
                const int row = wv * 32 + mi * 16 + crow + j;
                outp[((size_t)kz * B + row) * NOUT + col] = acc[mi][ni][j];
            }
        }
}

// ---------------------------------------------------------------------------
// LSTM cell: sums 2 gate partials + biases, gates, writes hx_new f32 and
// its bf16 hi/lo into the GEMM-1 A buffer (cols 2048..4095).
// ---------------------------------------------------------------------------
__global__ __launch_bounds__(256) void lstm_cell(
    const float* __restrict__ gp,     // [2][128][8192]
    const float* __restrict__ cx,
    const float* __restrict__ b_ih,
    const float* __restrict__ b_hh,
    float* __restrict__ hxn,
    u16* __restrict__ Ah1, u16* __restrict__ Al1)
{
    const int t = blockIdx.x * 256 + threadIdx.x;   // 65536 threads
    const int b = t >> 9;
    const int h = (t & 511) * 4;
    const float* g0 = gp + (size_t)b * FOURH;
    const float* g1 = g0 + (size_t)B * FOURH;
    f32x4 gi = *(const f32x4*)(g0 + h)         + *(const f32x4*)(g1 + h)
             + *(const f32x4*)(b_ih + h)       + *(const f32x4*)(b_hh + h);
    f32x4 gf = *(const f32x4*)(g0 + H + h)     + *(const f32x4*)(g1 + H + h)
             + *(const f32x4*)(b_ih + H + h)   + *(const f32x4*)(b_hh + H + h);
    f32x4 gg = *(const f32x4*)(g0 + 2*H + h)   + *(const f32x4*)(g1 + 2*H + h)
             + *(const f32x4*)(b_ih + 2*H + h) + *(const f32x4*)(b_hh + 2*H + h);
    f32x4 go = *(const f32x4*)(g0 + 3*H + h)   + *(const f32x4*)(g1 + 3*H + h)
             + *(const f32x4*)(b_ih + 3*H + h) + *(const f32x4*)(b_hh + 3*H + h);
    f32x4 cv = *(const f32x4*)(cx + (size_t)b * H + h);
    f32x4 hv;
    #pragma unroll
    for (int j = 0; j < 4; ++j) {
        float i_ = 1.f / (1.f + expf(-gi[j]));
        float f_ = 1.f / (1.f + expf(-gf[j]));
        float o_ = 1.f / (1.f + expf(-go[j]));
        float g_ = tanhf(gg[j]);
        float c_ = f_ * cv[j] + i_ * g_;
        hv[j] = o_ * tanhf(c_);
    }
    *(f32x4*)(hxn + (size_t)b * H + h) = hv;
    u16x4 hh, ll;
    #pragma unroll
    for (int j = 0; j < 4; ++j) { u16 a, l; cvt_hilo(hv[j], a, l); hh[j] = a; ll[j] = l; }
    *(u16x4*)(Ah1 + (size_t)b * 4096 + H + h) = hh;
    *(u16x4*)(Al1 + (size_t)b * 4096 + H + h) = ll;
}

// ---------------------------------------------------------------------------
// Fused attention: one pass over ew, online softmax (flash-style).
// Grid: 512 blocks = 128 b x 4 chunks of 128 s. Wave w owns 32 s.
// ---------------------------------------------------------------------------
__global__ __launch_bounds__(256) void fused_attn(
    const float* __restrict__ hxn,     // [128][2048]
    const float* __restrict__ ew,      // [512][128][2048]
    const int* __restrict__ mask,      // [512][128]
    float* __restrict__ o_part,        // [128][4][2048] unnormalized
    float* __restrict__ ml_part)       // [128][4][2] = (M, L)
{
    __shared__ float mlbuf[4][2];
    __shared__ float obuf[4][2048];

    const int tid = threadIdx.x;
    const int b = blockIdx.x >> 2;
    const int c = blockIdx.x & 3;
    const int wv = tid >> 6;
    const int lane = tid & 63;
    const int s0 = c * 128 + wv * 32;

    // mask bits for this wave's 32 s-values
    unsigned long long mbits;
    {
        int mv = (lane < 32) ? mask[(s0 + lane) * B + b] : 0;
        mbits = __ballot(mv != 0);
    }

    f32x4 hxv[8];
    const float* hp = hxn + (size_t)b * H + lane * 4;
    #pragma unroll
    for (int j = 0; j < 8; ++j) hxv[j] = *(const f32x4*)(hp + j * 256);

    f32x4 o4[8];
    #pragma unroll
    for (int j = 0; j < 8; ++j) o4[j] = (f32x4){0.f, 0.f, 0.f, 0.f};
    float m = -3.0e38f, l = 0.f;

    const size_t SSTRIDE = (size_t)B * H;
    const float* rowp = ew + ((size_t)s0 * B + b) * H + lane * 4;

    f32x4 ev[8];
    #pragma unroll
    for (int j = 0; j < 8; ++j) ev[j] = *(const f32x4*)(rowp + j * 256);

    for (int si = 0; si < 32; ++si) {
        f32x4 cur[8];
        #pragma unroll
        for (int j = 0; j < 8; ++j) cur[j] = ev[j];
        if (si < 31) {
            const float* np = rowp + (size_t)(si + 1) * SSTRIDE;
            #pragma unroll
            for (int j = 0; j < 8; ++j) ev[j] = *(const f32x4*)(np + j * 256);
        }
        float p = 0.f;
        #pragma unroll
        for (int j = 0; j < 8; ++j) {
            f32x4 t = cur[j] * hxv[j];
            p += t[0] + t[1] + t[2] + t[3];
        }
        #pragma unroll
        for (int off = 32; off; off >>= 1) p += __shfl_xor(p, off, 64);
        if (!((mbits >> si) & 1)) p = -1e9f;
        const float mn = fmaxf(m, p);
        const float sc = expf(m - mn);
        const float pe = expf(p - mn);
        l = l * sc + pe;
        #pragma unroll
        for (int j = 0; j < 8; ++j) o4[j] = o4[j] * sc + cur[j] * pe;
        m = mn;
    }

    if (lane == 0) { mlbuf[wv][0] = m; mlbuf[wv][1] = l; }
    __syncthreads();
    const float M = fmaxf(fmaxf(mlbuf[0][0], mlbuf[1][0]), fmaxf(mlbuf[2][0], mlbuf[3][0]));
    const float wsc = expf(m - M);
    float L = 0.f;
    #pragma unroll
    for (int w = 0; w < 4; ++w) L += mlbuf[w][1] * expf(mlbuf[w][0] - M);
    #pragma unroll
    for (int j = 0; j < 8; ++j)
        *(f32x4*)&obuf[wv][j * 256 + lane * 4] = o4[j] * wsc;
    __syncthreads();

    const int h0 = tid * 8;
    f32x4 s0v = (f32x4){0.f, 0.f, 0.f, 0.f}, s1v = s0v;
    #pragma unroll
    for (int w = 0; w < 4; ++w) {
        s0v += *(const f32x4*)&obuf[w][h0];
        s1v += *(const f32x4*)&obuf[w][h0 + 4];
    }
    float* op = o_part + ((size_t)b * 4 + c) * H + h0;
    *(f32x4*)(op)     = s0v;
    *(f32x4*)(op + 4) = s1v;
    if (tid == 0) {
        ml_part[((size_t)b * 4 + c) * 2]     = M;
        ml_part[((size_t)b * 4 + c) * 2 + 1] = L;
    }
}

// ---------------------------------------------------------------------------
// Combine 4 chunk-partials -> content, written as bf16 hi/lo into A1[:,0:2048]
// ---------------------------------------------------------------------------
__global__ __launch_bounds__(256) void attn_combine(
    const float* __restrict__ o_part,
    const float* __restrict__ ml_part,
    u16* __restrict__ Ah1, u16* __restrict__ Al1)
{
    const int b = blockIdx.x;
    const int tid = threadIdx.x;
    float Mc[4], Lc[4];
    #pragma unroll
    for (int c = 0; c < 4; ++c) {
        Mc[c] = ml_part[((size_t)b * 4 + c) * 2];
        Lc[c] = ml_part[((size_t)b * 4 + c) * 2 + 1];
    }
    const float Mg = fmaxf(fmaxf(Mc[0], Mc[1]), fmaxf(Mc[2], Mc[3]));
    float Lg = 0.f;
    #pragma unroll
    for (int c = 0; c < 4; ++c) Lg += Lc[c] * expf(Mc[c] - Mg);
    const float inv = 1.f / Lg;
    const int h0 = tid * 8;
    f32x4 a0 = (f32x4){0.f, 0.f, 0.f, 0.f}, a1 = a0;
    #pragma unroll
    for (int c = 0; c < 4; ++c) {
        const float scl = expf(Mc[c] - Mg) * inv;
        const float* op = o_part + ((size_t)b * 4 + c) * H + h0;
        a0 += *(const f32x4*)(op) * scl;
        a1 += *(const f32x4*)(op + 4) * scl;
    }
    u16x8 hh, ll;
    #pragma unroll
    for (int j = 0; j < 4; ++j) { u16 a, l; cvt_hilo(a0[j], a, l); hh[j] = a; ll[j] = l; }
    #pragma unroll
    for (int j = 0; j < 4; ++j) { u16 a, l; cvt_hilo(a1[j], a, l); hh[4+j] = a; ll[4+j] = l; }
    *(u16x8*)(Ah1 + (size_t)b * 4096 + h0) = hh;
    *(u16x8*)(Al1 + (size_t)b * 4096 + h0) = ll;
}

// ---------------------------------------------------------------------------
// Output epilogue: out = tanh(sum of 4 K-partials + attn_b)
// ---------------------------------------------------------------------------
__global__ __launch_bounds__(256) void attn_out(
    const float* __restrict__ part,    // [4][128][2048]
    const float* __restrict__ attn_b,
    float* __restrict__ out)
{
    const int t = blockIdx.x * 256 + threadIdx.x;   // 65536 threads
    const int i = t * 4;
    const int n = i & (H - 1);
    const size_t BH = (size_t)B * H;
    f32x4 s = *(const f32x4*)(part + i)
            + *(const f32x4*)(part + BH + i)
            + *(const f32x4*)(part + 2 * BH + i)
            + *(const f32x4*)(part + 3 * BH + i)
            + *(const f32x4*)(attn_b + n);
    f32x4 r;
    #pragma unroll
    for (int j = 0; j < 4; ++j) r[j] = tanhf(s[j]);
    *(f32x4*)(out + i) = r;
}

// ---------------------------------------------------------------------------
extern "C" void kernel_launch(void* const* d_in, const int* in_sizes, int n_in,
                              void* d_out, int out_size, void* d_ws, size_t ws_size,
                              hipStream_t stream)
{
    const int*   tw     = (const int*)d_in[0];
    const float* hx     = (const float*)d_in[1];
    const float* cx     = (const float*)d_in[2];
    const float* ew     = (const float*)d_in[3];
    const int*   mask   = (const int*)d_in[4];
    const float* embed  = (const float*)d_in[5];
    const float* W_ih   = (const float*)d_in[6];
    const float* W_hh   = (const float*)d_in[7];
    const float* b_ih   = (const float*)d_in[8];
    const float* b_hh   = (const float*)d_in[9];
    const float* attn_W = (const float*)d_in[10];
    const float* attn_b = (const float*)d_in[11];
    float* out = (float*)d_out;

    float* ws      = (float*)d_ws;
    float* gates_p = ws;                                  // 2*128*8192
    float* o_part  = gates_p + 2 * (size_t)B * FOURH;     // 128*4*2048
    float* ml      = o_part + (size_t)B * 4 * H;          // 1024
    float* hxn     = ml + 1024;                           // 128*2048
    float* out_p   = hxn + (size_t)B * H;                 // 4*128*2048
    u16* Ah0 = (u16*)(out_p + 4 * (size_t)B * H);
    u16* Al0 = Ah0 + (size_t)B * 4096;
    u16* Ah1 = Al0 + (size_t)B * 4096;
    u16* Al1 = Ah1 + (size_t)B * 4096;

    gather_convert_A0<<<256, 256, 0, stream>>>(tw, embed, hx, Ah0, Al0);
    split_gemm<0><<<dim3(FOURH / 32, 2), 256, 0, stream>>>(Ah0, Al0, W_ih, W_hh, gates_p);
    lstm_cell<<<256, 256, 0, stream>>>(gates_p, cx, b_ih, b_hh, hxn, Ah1, Al1);
    fused_attn<<<B * 4, 256, 0, stream>>>(hxn, ew, mask, o_part, ml);
    attn_combine<<<B, 256, 0, stream>>>(o_part, ml, Ah1, Al1);
    split_gemm<1><<<dim3(H / 32, 4), 256, 0, stream>>>(Ah1, Al1, attn_W, attn_W, out_p);
    attn_out<<<256, 256, 0, stream>>>(out_p, attn_b, out);
}

// Round 4
// 221.246 us; speedup vs baseline: 2.8577x; 1.0431x over previous
//
#include <hip/hip_runtime.h>
#include <math.h>

#define B 128
#define H 2048
#define S 512
#define FOURH 8192
#define LOG2E 1.4426950408889634f

typedef float  f32x4  __attribute__((ext_vector_type(4)));
typedef short  bf16x8 __attribute__((ext_vector_type(8)));
typedef unsigned short u16;
typedef unsigned short u16x8 __attribute__((ext_vector_type(8)));
typedef unsigned short u16x4 __attribute__((ext_vector_type(4)));

// Split f32 -> bf16 hi + bf16 lo (truncation; lo captures residual, total ~2^-16)
__device__ __forceinline__ void cvt_hilo(float x, u16& h, u16& lo) {
    unsigned int u = __float_as_uint(x);
    h = (u16)(u >> 16);
    float hf = __uint_as_float(u & 0xFFFF0000u);
    float r = x - hf;
    lo = (u16)(__float_as_uint(r) >> 16);
}

// ---------------------------------------------------------------------------
// Kernel 1: build A0 = [embed[tw] | hx] as bf16 hi/lo pair [128][4096]
// ---------------------------------------------------------------------------
__global__ __launch_bounds__(256) void gather_convert_A0(
    const int* __restrict__ tw,
    const float* __restrict__ embed,
    const float* __restrict__ hx,
    u16* __restrict__ Ah, u16* __restrict__ Al)
{
    const int i = (blockIdx.x * 256 + threadIdx.x) * 8;   // over 128*4096
    const int b = i >> 12;
    const int col = i & 4095;
    const float* src = (col < H) ? (embed + (size_t)tw[b] * H + col)
                                 : (hx + (size_t)b * H + (col - H));
    f32x4 v0 = *(const f32x4*)(src);
    f32x4 v1 = *(const f32x4*)(src + 4);
    u16x8 hv, lv;
    #pragma unroll
    for (int j = 0; j < 4; ++j) { u16 h, l; cvt_hilo(v0[j], h, l); hv[j] = h; lv[j] = l; }
    #pragma unroll
    for (int j = 0; j < 4; ++j) { u16 h, l; cvt_hilo(v1[j], h, l); hv[4+j] = h; lv[4+j] = l; }
    *(u16x8*)(Ah + i) = hv;
    *(u16x8*)(Al + i) = lv;
}

// ---------------------------------------------------------------------------
// Split-bf16 MFMA GEMM with split-K (partials; no bias/activation here).
// BM=128, BN=32, BK=32, 256 threads (4 waves), wave w owns rows w*32..+31.
// 3 MFMA per tile pair: Ah*Wh + Ah*Wl + Al*Wh (err ~2^-16).
// MODE 0: K=4096 split 4; kz 0,1 -> W_ih halves, kz 2,3 -> W_hh halves.
//         out [4][128][8192]
// MODE 1: K=4096 split 8 over attn_W [2048][4096]; out [8][128][2048]
// ---------------------------------------------------------------------------
template<int MODE>
__global__ __launch_bounds__(256) void split_gemm(
    const u16* __restrict__ Ah, const u16* __restrict__ Al,
    const float* __restrict__ W0, const float* __restrict__ W1,
    float* __restrict__ outp)
{
    constexpr int NOUT = (MODE == 0) ? FOURH : H;
    constexpr int KLEN = (MODE == 0) ? 1024 : 512;
    __shared__ u16 AhS[128][40];
    __shared__ u16 AlS[128][40];
    __shared__ u16 BhS[32][40];
    __shared__ u16 BlS[32][40];

    const int tid = threadIdx.x;
    const int n0 = blockIdx.x * 32;
    const int kz = blockIdx.y;
    const int kbase = kz * KLEN;
    const int ar = tid >> 1, ac = (tid & 1) * 16;
    const int br = tid >> 3, bc = (tid & 7) * 4;
    const int wv = tid >> 6, lane = tid & 63;
    const int frow = lane & 15, fk = (lane >> 4) * 8, crow = (lane >> 4) * 4;

    const float* Wrow;
    if (MODE == 0)
        Wrow = ((kz < 2) ? W0 : W1) + (size_t)(n0 + br) * H + (kz & 1) * 1024;
    else
        Wrow = W0 + (size_t)(n0 + br) * (2 * H) + kbase;

    const u16* Abase = Ah + (size_t)ar * 4096 + kbase + ac;
    const u16* Lbase = Al + (size_t)ar * 4096 + kbase + ac;

    f32x4 acc[2][2];
    #pragma unroll
    for (int mi = 0; mi < 2; ++mi)
        #pragma unroll
        for (int ni = 0; ni < 2; ++ni)
            acc[mi][ni] = (f32x4){0.f, 0.f, 0.f, 0.f};

    u16x8 rah0, rah1, ral0, ral1;
    f32x4 rbv;
    auto load_tile = [&](int k0) {
        rah0 = *(const u16x8*)(Abase + k0);
        rah1 = *(const u16x8*)(Abase + k0 + 8);
        ral0 = *(const u16x8*)(Lbase + k0);
        ral1 = *(const u16x8*)(Lbase + k0 + 8);
        rbv  = *(const f32x4*)(Wrow + k0 + bc);
    };

    load_tile(0);

    for (int ks = 0; ks < KLEN / 32; ++ks) {
        __syncthreads();
        *(u16x8*)&AhS[ar][ac]     = rah0;
        *(u16x8*)&AhS[ar][ac + 8] = rah1;
        *(u16x8*)&AlS[ar][ac]     = ral0;
        *(u16x8*)&AlS[ar][ac + 8] = ral1;
        u16x4 bh, bl;
        #pragma unroll
        for (int j = 0; j < 4; ++j) { u16 h, l; cvt_hilo(rbv[j], h, l); bh[j] = h; bl[j] = l; }
        *(u16x4*)&BhS[br][bc] = bh;
        *(u16x4*)&BlS[br][bc] = bl;
        __syncthreads();
        if (ks + 1 < KLEN / 32) load_tile((ks + 1) * 32);

        bf16x8 a_h[2], a_l[2], b_h[2], b_l[2];
        #pragma unroll
        for (int mi = 0; mi < 2; ++mi) {
            a_h[mi] = *(const bf16x8*)&AhS[wv * 32 + mi * 16 + frow][fk];
            a_l[mi] = *(const bf16x8*)&AlS[wv * 32 + mi * 16 + frow][fk];
        }
        #pragma unroll
        for (int ni = 0; ni < 2; ++ni) {
            b_h[ni] = *(const bf16x8*)&BhS[ni * 16 + frow][fk];
            b_l[ni] = *(const bf16x8*)&BlS[ni * 16 + frow][fk];
        }
        #pragma unroll
        for (int mi = 0; mi < 2; ++mi)
            #pragma unroll
            for (int ni = 0; ni < 2; ++ni) {
                acc[mi][ni] = __builtin_amdgcn_mfma_f32_16x16x32_bf16(a_h[mi], b_h[ni], acc[mi][ni], 0, 0, 0);
                acc[mi][ni] = __builtin_amdgcn_mfma_f32_16x16x32_bf16(a_h[mi], b_l[ni], acc[mi][ni], 0, 0, 0);
                acc[mi][ni] = __builtin_amdgcn_mfma_f32_16x16x32_bf16(a_l[mi], b_h[ni], acc[mi][ni], 0, 0, 0);
            }
    }

    // C/D layout: col=lane&15, row=(lane>>4)*4+j  [m89/m91]
    #pragma unroll
    for (int mi = 0; mi < 2; ++mi)
        #pragma unroll
        for (int ni = 0; ni < 2; ++ni) {
            const int col = n0 + ni * 16 + frow;
            #pragma unroll
            for (int j = 0; j < 4; ++j) {
                const int row = wv * 32 + mi * 16 + crow + j;
                outp[((size_t)kz * B + row) * NOUT + col] = acc[mi][ni][j];
            }
        }
}

// ---------------------------------------------------------------------------
// LSTM cell: sums 4 gate partials + biases, gates, writes hx_new f32 and
// its bf16 hi/lo into the GEMM-1 A buffer (cols 2048..4095).
// ---------------------------------------------------------------------------
__global__ __launch_bounds__(256) void lstm_cell(
    const float* __restrict__ gp,     // [4][128][8192]
    const float* __restrict__ cx,
    const float* __restrict__ b_ih,
    const float* __restrict__ b_hh,
    float* __restrict__ hxn,
    u16* __restrict__ Ah1, u16* __restrict__ Al1)
{
    const int t = blockIdx.x * 256 + threadIdx.x;   // 65536 threads
    const int b = t >> 9;
    const int h = (t & 511) * 4;
    const size_t PS = (size_t)B * FOURH;
    const float* g0 = gp + (size_t)b * FOURH;
    f32x4 gi = *(const f32x4*)(b_ih + h)       + *(const f32x4*)(b_hh + h);
    f32x4 gf = *(const f32x4*)(b_ih + H + h)   + *(const f32x4*)(b_hh + H + h);
    f32x4 gg = *(const f32x4*)(b_ih + 2*H + h) + *(const f32x4*)(b_hh + 2*H + h);
    f32x4 go = *(const f32x4*)(b_ih + 3*H + h) + *(const f32x4*)(b_hh + 3*H + h);
    #pragma unroll
    for (int p = 0; p < 4; ++p) {
        gi += *(const f32x4*)(g0 + p * PS + h);
        gf += *(const f32x4*)(g0 + p * PS + H + h);
        gg += *(const f32x4*)(g0 + p * PS + 2*H + h);
        go += *(const f32x4*)(g0 + p * PS + 3*H + h);
    }
    f32x4 cv = *(const f32x4*)(cx + (size_t)b * H + h);
    f32x4 hv;
    #pragma unroll
    for (int j = 0; j < 4; ++j) {
        float i_ = 1.f / (1.f + expf(-gi[j]));
        float f_ = 1.f / (1.f + expf(-gf[j]));
        float o_ = 1.f / (1.f + expf(-go[j]));
        float g_ = tanhf(gg[j]);
        float c_ = f_ * cv[j] + i_ * g_;
        hv[j] = o_ * tanhf(c_);
    }
    *(f32x4*)(hxn + (size_t)b * H + h) = hv;
    u16x4 hh, ll;
    #pragma unroll
    for (int j = 0; j < 4; ++j) { u16 a, l; cvt_hilo(hv[j], a, l); hh[j] = a; ll[j] = l; }
    *(u16x4*)(Ah1 + (size_t)b * 4096 + H + h) = hh;
    *(u16x4*)(Al1 + (size_t)b * 4096 + H + h) = ll;
}

// ---------------------------------------------------------------------------
// Fused attention: one pass over ew, online softmax in log2 domain.
// Grid: 512 blocks = 128 b x 4 chunks of 128 s. Wave w owns 32 s.
// Defer-rescale: o-accumulator rescale only when a new max appears
// (wave-uniform branch; exact).
// ---------------------------------------------------------------------------
__global__ __launch_bounds__(256) void fused_attn(
    const float* __restrict__ hxn,     // [128][2048]
    const float* __restrict__ ew,      // [512][128][2048]
    const int* __restrict__ mask,      // [512][128]
    float* __restrict__ o_part,        // [128][4][2048] unnormalized
    float* __restrict__ ml_part)       // [128][4][2] = (M2, L) log2-domain
{
    __shared__ float mlbuf[4][2];
    __shared__ float obuf[4][2048];

    const int tid = threadIdx.x;
    const int b = blockIdx.x >> 2;
    const int c = blockIdx.x & 3;
    const int wv = tid >> 6;
    const int lane = tid & 63;
    const int s0 = c * 128 + wv * 32;

    // mask bits for this wave's 32 s-values
    unsigned long long mbits;
    {
        int mv = (lane < 32) ? mask[(s0 + lane) * B + b] : 0;
        mbits = __ballot(mv != 0);
    }

    f32x4 hxv[8];
    const float* hp = hxn + (size_t)b * H + lane * 4;
    #pragma unroll
    for (int j = 0; j < 8; ++j) hxv[j] = *(const f32x4*)(hp + j * 256);

    f32x4 o4[8];
    #pragma unroll
    for (int j = 0; j < 8; ++j) o4[j] = (f32x4){0.f, 0.f, 0.f, 0.f};
    float m2 = -3.0e38f, l = 0.f;

    const size_t SSTRIDE = (size_t)B * H;
    const float* rowp = ew + ((size_t)s0 * B + b) * H + lane * 4;

    f32x4 ev[8];
    #pragma unroll
    for (int j = 0; j < 8; ++j) ev[j] = *(const f32x4*)(rowp + j * 256);

    for (int si = 0; si < 32; ++si) {
        f32x4 cur[8];
        #pragma unroll
        for (int j = 0; j < 8; ++j) cur[j] = ev[j];
        if (si < 31) {
            const float* np = rowp + (size_t)(si + 1) * SSTRIDE;
            #pragma unroll
            for (int j = 0; j < 8; ++j) ev[j] = *(const f32x4*)(np + j * 256);
        }
        float p = 0.f;
        #pragma unroll
        for (int j = 0; j < 8; ++j) {
            f32x4 t = cur[j] * hxv[j];
            p += t[0] + t[1] + t[2] + t[3];
        }
        #pragma unroll
        for (int off = 32; off; off >>= 1) p += __shfl_xor(p, off, 64);
        float p2 = ((mbits >> si) & 1) ? p * LOG2E : -1.5e9f;
        if (p2 <= m2) {
            // common path: no new max, no rescale
            const float pe = exp2f(p2 - m2);
            l += pe;
            #pragma unroll
            for (int j = 0; j < 8; ++j) o4[j] += cur[j] * pe;
        } else {
            const float sc = exp2f(m2 - p2);
            l = l * sc + 1.f;
            #pragma unroll
            for (int j = 0; j < 8; ++j) o4[j] = o4[j] * sc + cur[j];
            m2 = p2;
        }
    }

    if (lane == 0) { mlbuf[wv][0] = m2; mlbuf[wv][1] = l; }
    __syncthreads();
    const float M = fmaxf(fmaxf(mlbuf[0][0], mlbuf[1][0]), fmaxf(mlbuf[2][0], mlbuf[3][0]));
    const float wsc = exp2f(m2 - M);
    float L = 0.f;
    #pragma unroll
    for (int w = 0; w < 4; ++w) L += mlbuf[w][1] * exp2f(mlbuf[w][0] - M);
    #pragma unroll
    for (int j = 0; j < 8; ++j)
        *(f32x4*)&obuf[wv][j * 256 + lane * 4] = o4[j] * wsc;
    __syncthreads();

    const int h0 = tid * 8;
    f32x4 s0v = (f32x4){0.f, 0.f, 0.f, 0.f}, s1v = s0v;
    #pragma unroll
    for (int w = 0; w < 4; ++w) {
        s0v += *(const f32x4*)&obuf[w][h0];
        s1v += *(const f32x4*)&obuf[w][h0 + 4];
    }
    float* op = o_part + ((size_t)b * 4 + c) * H + h0;
    *(f32x4*)(op)     = s0v;
    *(f32x4*)(op + 4) = s1v;
    if (tid == 0) {
        ml_part[((size_t)b * 4 + c) * 2]     = M;
        ml_part[((size_t)b * 4 + c) * 2 + 1] = L;
    }
}

// ---------------------------------------------------------------------------
// Combine 4 chunk-partials -> content, written as bf16 hi/lo into A1[:,0:2048]
// ---------------------------------------------------------------------------
__global__ __launch_bounds__(256) void attn_combine(
    const float* __restrict__ o_part,
    const float* __restrict__ ml_part,
    u16* __restrict__ Ah1, u16* __restrict__ Al1)
{
    const int b = blockIdx.x;
    const int tid = threadIdx.x;
    float Mc[4], Lc[4];
    #pragma unroll
    for (int c = 0; c < 4; ++c) {
        Mc[c] = ml_part[((size_t)b * 4 + c) * 2];
        Lc[c] = ml_part[((size_t)b * 4 + c) * 2 + 1];
    }
    const float Mg = fmaxf(fmaxf(Mc[0], Mc[1]), fmaxf(Mc[2], Mc[3]));
    float Lg = 0.f;
    #pragma unroll
    for (int c = 0; c < 4; ++c) Lg += Lc[c] * exp2f(Mc[c] - Mg);
    const float inv = 1.f / Lg;
    const int h0 = tid * 8;
    f32x4 a0 = (f32x4){0.f, 0.f, 0.f, 0.f}, a1 = a0;
    #pragma unroll
    for (int c = 0; c < 4; ++c) {
        const float scl = exp2f(Mc[c] - Mg) * inv;
        const float* op = o_part + ((size_t)b * 4 + c) * H + h0;
        a0 += *(const f32x4*)(op) * scl;
        a1 += *(const f32x4*)(op + 4) * scl;
    }
    u16x8 hh, ll;
    #pragma unroll
    for (int j = 0; j < 4; ++j) { u16 a, l; cvt_hilo(a0[j], a, l); hh[j] = a; ll[j] = l; }
    #pragma unroll
    for (int j = 0; j < 4; ++j) { u16 a, l; cvt_hilo(a1[j], a, l); hh[4+j] = a; ll[4+j] = l; }
    *(u16x8*)(Ah1 + (size_t)b * 4096 + h0) = hh;
    *(u16x8*)(Al1 + (size_t)b * 4096 + h0) = ll;
}

// ---------------------------------------------------------------------------
// Output epilogue: out = tanh(sum of 8 K-partials + attn_b)
// ---------------------------------------------------------------------------
__global__ __launch_bounds__(256) void attn_out(
    const float* __restrict__ part,    // [8][128][2048]
    const float* __restrict__ attn_b,
    float* __restrict__ out)
{
    const int t = blockIdx.x * 256 + threadIdx.x;   // 65536 threads
    const int i = t * 4;
    const int n = i & (H - 1);
    const size_t BH = (size_t)B * H;
    f32x4 s = *(const f32x4*)(attn_b + n);
    #pragma unroll
    for (int p = 0; p < 8; ++p) s += *(const f32x4*)(part + p * BH + i);
    f32x4 r;
    #pragma unroll
    for (int j = 0; j < 4; ++j) r[j] = tanhf(s[j]);
    *(f32x4*)(out + i) = r;
}

// ---------------------------------------------------------------------------
extern "C" void kernel_launch(void* const* d_in, const int* in_sizes, int n_in,
                              void* d_out, int out_size, void* d_ws, size_t ws_size,
                              hipStream_t stream)
{
    const int*   tw     = (const int*)d_in[0];
    const float* hx     = (const float*)d_in[1];
    const float* cx     = (const float*)d_in[2];
    const float* ew     = (const float*)d_in[3];
    const int*   mask   = (const int*)d_in[4];
    const float* embed  = (const float*)d_in[5];
    const float* W_ih   = (const float*)d_in[6];
    const float* W_hh   = (const float*)d_in[7];
    const float* b_ih   = (const float*)d_in[8];
    const float* b_hh   = (const float*)d_in[9];
    const float* attn_W = (const float*)d_in[10];
    const float* attn_b = (const float*)d_in[11];
    float* out = (float*)d_out;

    float* ws      = (float*)d_ws;
    float* gates_p = ws;                                  // 4*128*8192
    float* o_part  = gates_p + 4 * (size_t)B * FOURH;     // 128*4*2048
    float* ml      = o_part + (size_t)B * 4 * H;          // 1024
    float* hxn     = ml + 1024;                           // 128*2048
    float* out_p   = hxn + (size_t)B * H;                 // 8*128*2048
    u16* Ah0 = (u16*)(out_p + 8 * (size_t)B * H);
    u16* Al0 = Ah0 + (size_t)B * 4096;
    u16* Ah1 = Al0 + (size_t)B * 4096;
    u16* Al1 = Ah1 + (size_t)B * 4096;

    gather_convert_A0<<<256, 256, 0, stream>>>(tw, embed, hx, Ah0, Al0);
    split_gemm<0><<<dim3(FOURH / 32, 4), 256, 0, stream>>>(Ah0, Al0, W_ih, W_hh, gates_p);
    lstm_cell<<<256, 256, 0, stream>>>(gates_p, cx, b_ih, b_hh, hxn, Ah1, Al1);
    fused_attn<<<B * 4, 256, 0, stream>>>(hxn, ew, mask, o_part, ml);
    attn_combine<<<B, 256, 0, stream>>>(o_part, ml, Ah1, Al1);
    split_gemm<1><<<dim3(H / 32, 8), 256, 0, stream>>>(Ah1, Al1, attn_W, attn_W, out_p);
    attn_out<<<256, 256, 0, stream>>>(out_p, attn_b, out);
}

// Round 5
// 214.255 us; speedup vs baseline: 2.9510x; 1.0326x over previous
//
#include <hip/hip_runtime.h>
#include <math.h>

#define B 128
#define H 2048
#define S 512
#define FOURH 8192
#define LOG2E 1.4426950408889634f

typedef float  f32x4  __attribute__((ext_vector_type(4)));
typedef short  bf16x8 __attribute__((ext_vector_type(8)));
typedef unsigned short u16;
typedef unsigned short u16x8 __attribute__((ext_vector_type(8)));
typedef unsigned short u16x4 __attribute__((ext_vector_type(4)));

// Split f32 -> bf16 hi + bf16 lo (truncation; lo captures residual, total ~2^-16)
__device__ __forceinline__ void cvt_hilo(float x, u16& h, u16& lo) {
    unsigned int u = __float_as_uint(x);
    h = (u16)(u >> 16);
    float hf = __uint_as_float(u & 0xFFFF0000u);
    float r = x - hf;
    lo = (u16)(__float_as_uint(r) >> 16);
}

// ---------------------------------------------------------------------------
// Kernel 1: build A0 = [embed[tw] | hx] as bf16 hi/lo pair [128][4096]
// ---------------------------------------------------------------------------
__global__ __launch_bounds__(256) void gather_convert_A0(
    const int* __restrict__ tw,
    const float* __restrict__ embed,
    const float* __restrict__ hx,
    u16* __restrict__ Ah, u16* __restrict__ Al)
{
    const int i = (blockIdx.x * 256 + threadIdx.x) * 8;   // over 128*4096
    const int b = i >> 12;
    const int col = i & 4095;
    const float* src = (col < H) ? (embed + (size_t)tw[b] * H + col)
                                 : (hx + (size_t)b * H + (col - H));
    f32x4 v0 = *(const f32x4*)(src);
    f32x4 v1 = *(const f32x4*)(src + 4);
    u16x8 hv, lv;
    #pragma unroll
    for (int j = 0; j < 4; ++j) { u16 h, l; cvt_hilo(v0[j], h, l); hv[j] = h; lv[j] = l; }
    #pragma unroll
    for (int j = 0; j < 4; ++j) { u16 h, l; cvt_hilo(v1[j], h, l); hv[4+j] = h; lv[4+j] = l; }
    *(u16x8*)(Ah + i) = hv;
    *(u16x8*)(Al + i) = lv;
}

// ---------------------------------------------------------------------------
// Split-bf16 MFMA GEMM with split-K (partials; no bias/activation here).
// BM=128, BN=32, BK=32, 256 threads (4 waves). 2-deep W prefetch (K-loop
// unrolled x2, named rbvX/rbvY) so the HBM W-load has ~2 iterations to land.
// MODE 0: K=4096 split 4; kz 0,1 -> W_ih halves, kz 2,3 -> W_hh halves.
// MODE 1: K=4096 split 8 over attn_W [2048][4096]; out [8][128][2048]
// ---------------------------------------------------------------------------
template<int MODE>
__global__ __launch_bounds__(256) void split_gemm(
    const u16* __restrict__ Ah, const u16* __restrict__ Al,
    const float* __restrict__ W0, const float* __restrict__ W1,
    float* __restrict__ outp)
{
    constexpr int NOUT = (MODE == 0) ? FOURH : H;
    constexpr int KLEN = (MODE == 0) ? 1024 : 512;
    constexpr int NITER = KLEN / 32;
    __shared__ u16 AhS[128][40];
    __shared__ u16 AlS[128][40];
    __shared__ u16 BhS[32][40];
    __shared__ u16 BlS[32][40];

    const int tid = threadIdx.x;
    const int n0 = blockIdx.x * 32;
    const int kz = blockIdx.y;
    const int kbase = kz * KLEN;
    const int ar = tid >> 1, ac = (tid & 1) * 16;
    const int br = tid >> 3, bc = (tid & 7) * 4;
    const int wv = tid >> 6, lane = tid & 63;
    const int frow = lane & 15, fk = (lane >> 4) * 8, crow = (lane >> 4) * 4;

    const float* Wrow;
    if (MODE == 0)
        Wrow = ((kz < 2) ? W0 : W1) + (size_t)(n0 + br) * H + (kz & 1) * 1024 + bc;
    else
        Wrow = W0 + (size_t)(n0 + br) * (2 * H) + kbase + bc;

    const u16* Abase = Ah + (size_t)ar * 4096 + kbase + ac;
    const u16* Lbase = Al + (size_t)ar * 4096 + kbase + ac;

    f32x4 acc[2][2];
    #pragma unroll
    for (int mi = 0; mi < 2; ++mi)
        #pragma unroll
        for (int ni = 0; ni < 2; ++ni)
            acc[mi][ni] = (f32x4){0.f, 0.f, 0.f, 0.f};

    u16x8 rah0, rah1, ral0, ral1;
    auto loadA = [&](int k0) {
        rah0 = *(const u16x8*)(Abase + k0);
        rah1 = *(const u16x8*)(Abase + k0 + 8);
        ral0 = *(const u16x8*)(Lbase + k0);
        ral1 = *(const u16x8*)(Lbase + k0 + 8);
    };
    auto writeA = [&]() {
        *(u16x8*)&AhS[ar][ac]     = rah0;
        *(u16x8*)&AhS[ar][ac + 8] = rah1;
        *(u16x8*)&AlS[ar][ac]     = ral0;
        *(u16x8*)&AlS[ar][ac + 8] = ral1;
    };
    auto writeB = [&](f32x4 rbv) {
        u16x4 bh, bl;
        #pragma unroll
        for (int j = 0; j < 4; ++j) { u16 h, l; cvt_hilo(rbv[j], h, l); bh[j] = h; bl[j] = l; }
        *(u16x4*)&BhS[br][bc] = bh;
        *(u16x4*)&BlS[br][bc] = bl;
    };
    auto computeTile = [&]() {
        bf16x8 a_h[2], a_l[2], b_h[2], b_l[2];
        #pragma unroll
        for (int mi = 0; mi < 2; ++mi) {
            a_h[mi] = *(const bf16x8*)&AhS[wv * 32 + mi * 16 + frow][fk];
            a_l[mi] = *(const bf16x8*)&AlS[wv * 32 + mi * 16 + frow][fk];
        }
        #pragma unroll
        for (int ni = 0; ni < 2; ++ni) {
            b_h[ni] = *(const bf16x8*)&BhS[ni * 16 + frow][fk];
            b_l[ni] = *(const bf16x8*)&BlS[ni * 16 + frow][fk];
        }
        #pragma unroll
        for (int mi = 0; mi < 2; ++mi)
            #pragma unroll
            for (int ni = 0; ni < 2; ++ni) {
                acc[mi][ni] = __builtin_amdgcn_mfma_f32_16x16x32_bf16(a_h[mi], b_h[ni], acc[mi][ni], 0, 0, 0);
                acc[mi][ni] = __builtin_amdgcn_mfma_f32_16x16x32_bf16(a_h[mi], b_l[ni], acc[mi][ni], 0, 0, 0);
                acc[mi][ni] = __builtin_amdgcn_mfma_f32_16x16x32_bf16(a_l[mi], b_h[ni], acc[mi][ni], 0, 0, 0);
            }
    };

    f32x4 rbvX = *(const f32x4*)(Wrow);
    f32x4 rbvY = *(const f32x4*)(Wrow + 32);
    loadA(0);

    for (int ks = 0; ks < NITER; ks += 2) {
        // half 1: tile ks (A regs), weights rbvX
        __syncthreads();
        writeA();
        writeB(rbvX);
        __syncthreads();
        loadA((ks + 1) * 32);                 // tile ks+1 (always valid: NITER even)
        if (ks + 2 < NITER) rbvX = *(const f32x4*)(Wrow + (ks + 2) * 32);
        computeTile();
        // half 2: tile ks+1, weights rbvY
        __syncthreads();
        writeA();
        writeB(rbvY);
        __syncthreads();
        if (ks + 2 < NITER) loadA((ks + 2) * 32);
        if (ks + 3 < NITER) rbvY = *(const f32x4*)(Wrow + (ks + 3) * 32);
        computeTile();
    }

    // C/D layout: col=lane&15, row=(lane>>4)*4+j  [m89/m91]
    #pragma unroll
    for (int mi = 0; mi < 2; ++mi)
        #pragma unroll
        for (int ni = 0; ni < 2; ++ni) {
            const int col = n0 + ni * 16 + frow;
            #pragma unroll
            for (int j = 0; j < 4; ++j) {
                const int row = wv * 32 + mi * 16 + crow + j;
                outp[((size_t)kz * B + row) * NOUT + col] = acc[mi][ni][j];
            }
        }
}

// ---------------------------------------------------------------------------
// LSTM cell: sums 4 gate partials + biases, gates, writes hx_new f32 and
// its bf16 hi/lo into the GEMM-1 A buffer (cols 2048..4095).
// ---------------------------------------------------------------------------
__global__ __launch_bounds__(256) void lstm_cell(
    const float* __restrict__ gp,     // [4][128][8192]
    const float* __restrict__ cx,
    const float* __restrict__ b_ih,
    const float* __restrict__ b_hh,
    float* __restrict__ hxn,
    u16* __restrict__ Ah1, u16* __restrict__ Al1)
{
    const int t = blockIdx.x * 256 + threadIdx.x;   // 65536 threads
    const int b = t >> 9;
    const int h = (t & 511) * 4;
    const size_t PS = (size_t)B * FOURH;
    const float* g0 = gp + (size_t)b * FOURH;
    f32x4 gi = *(const f32x4*)(b_ih + h)       + *(const f32x4*)(b_hh + h);
    f32x4 gf = *(const f32x4*)(b_ih + H + h)   + *(const f32x4*)(b_hh + H + h);
    f32x4 gg = *(const f32x4*)(b_ih + 2*H + h) + *(const f32x4*)(b_hh + 2*H + h);
    f32x4 go = *(const f32x4*)(b_ih + 3*H + h) + *(const f32x4*)(b_hh + 3*H + h);
    #pragma unroll
    for (int p = 0; p < 4; ++p) {
        gi += *(const f32x4*)(g0 + p * PS + h);
        gf += *(const f32x4*)(g0 + p * PS + H + h);
        gg += *(const f32x4*)(g0 + p * PS + 2*H + h);
        go += *(const f32x4*)(g0 + p * PS + 3*H + h);
    }
    f32x4 cv = *(const f32x4*)(cx + (size_t)b * H + h);
    f32x4 hv;
    #pragma unroll
    for (int j = 0; j < 4; ++j) {
        float i_ = 1.f / (1.f + expf(-gi[j]));
        float f_ = 1.f / (1.f + expf(-gf[j]));
        float o_ = 1.f / (1.f + expf(-go[j]));
        float g_ = tanhf(gg[j]);
        float c_ = f_ * cv[j] + i_ * g_;
        hv[j] = o_ * tanhf(c_);
    }
    *(f32x4*)(hxn + (size_t)b * H + h) = hv;
    u16x4 hh, ll;
    #pragma unroll
    for (int j = 0; j < 4; ++j) { u16 a, l; cvt_hilo(hv[j], a, l); hh[j] = a; ll[j] = l; }
    *(u16x4*)(Ah1 + (size_t)b * 4096 + H + h) = hh;
    *(u16x4*)(Al1 + (size_t)b * 4096 + H + h) = ll;
}

// ---------------------------------------------------------------------------
// Fused attention: one pass over ew, online softmax in log2 domain.
// Grid: 512 blocks = 128 b x 4 chunks of 128 s. Wave w owns 32 s, processed
// in PAIRS (2 rows/iter): 16 KB in flight, 2 independent dots + interleaved
// shfl chains per softmax-state update. Defer-rescale on the pair max.
// ---------------------------------------------------------------------------
__global__ __launch_bounds__(256) void fused_attn(
    const float* __restrict__ hxn,     // [128][2048]
    const float* __restrict__ ew,      // [512][128][2048]
    const int* __restrict__ mask,      // [512][128]
    float* __restrict__ o_part,        // [128][4][2048] unnormalized
    float* __restrict__ ml_part)       // [128][4][2] = (M2, L) log2-domain
{
    __shared__ float mlbuf[4][2];
    __shared__ float obuf[4][2048];

    const int tid = threadIdx.x;
    const int b = blockIdx.x >> 2;
    const int c = blockIdx.x & 3;
    const int wv = tid >> 6;
    const int lane = tid & 63;
    const int s0 = c * 128 + wv * 32;

    // mask bits for this wave's 32 s-values
    unsigned long long mbits;
    {
        int mv = (lane < 32) ? mask[(s0 + lane) * B + b] : 0;
        mbits = __ballot(mv != 0);
    }

    f32x4 hxv[8];
    const float* hp = hxn + (size_t)b * H + lane * 4;
    #pragma unroll
    for (int j = 0; j < 8; ++j) hxv[j] = *(const f32x4*)(hp + j * 256);

    f32x4 o4[8];
    #pragma unroll
    for (int j = 0; j < 8; ++j) o4[j] = (f32x4){0.f, 0.f, 0.f, 0.f};
    float m2 = -3.0e38f, l = 0.f;

    const size_t SSTRIDE = (size_t)B * H;
    const float* rowp = ew + ((size_t)s0 * B + b) * H + lane * 4;

    f32x4 eva[8], evb[8];
    #pragma unroll
    for (int j = 0; j < 8; ++j) eva[j] = *(const f32x4*)(rowp + j * 256);
    #pragma unroll
    for (int j = 0; j < 8; ++j) evb[j] = *(const f32x4*)(rowp + SSTRIDE + j * 256);

    for (int pi = 0; pi < 16; ++pi) {
        f32x4 ca[8], cb[8];
        #pragma unroll
        for (int j = 0; j < 8; ++j) { ca[j] = eva[j]; cb[j] = evb[j]; }
        if (pi < 15) {
            const float* na = rowp + (size_t)(2 * pi + 2) * SSTRIDE;
            const float* nb = rowp + (size_t)(2 * pi + 3) * SSTRIDE;
            #pragma unroll
            for (int j = 0; j < 8; ++j) eva[j] = *(const f32x4*)(na + j * 256);
            #pragma unroll
            for (int j = 0; j < 8; ++j) evb[j] = *(const f32x4*)(nb + j * 256);
        }
        float pa = 0.f, pb = 0.f;
        #pragma unroll
        for (int j = 0; j < 8; ++j) {
            f32x4 ta = ca[j] * hxv[j];
            f32x4 tb = cb[j] * hxv[j];
            pa += ta[0] + ta[1] + ta[2] + ta[3];
            pb += tb[0] + tb[1] + tb[2] + tb[3];
        }
        #pragma unroll
        for (int off = 32; off; off >>= 1) {
            pa += __shfl_xor(pa, off, 64);
            pb += __shfl_xor(pb, off, 64);
        }
        const float p2a = ((mbits >> (2 * pi)) & 1) ? pa * LOG2E : -1.5e9f;
        const float p2b = ((mbits >> (2 * pi + 1)) & 1) ? pb * LOG2E : -1.5e9f;
        const float q = fmaxf(p2a, p2b);
        if (q <= m2) {
            // common path: no new max, no o4 rescale
            const float ea = exp2f(p2a - m2);
            const float eb = exp2f(p2b - m2);
            l += ea + eb;
            #pragma unroll
            for (int j = 0; j < 8; ++j) o4[j] += ca[j] * ea + cb[j] * eb;
        } else {
            const float sc = exp2f(m2 - q);
            const float ea = exp2f(p2a - q);
            const float eb = exp2f(p2b - q);
            l = l * sc + ea + eb;
            #pragma unroll
            for (int j = 0; j < 8; ++j) o4[j] = o4[j] * sc + ca[j] * ea + cb[j] * eb;
            m2 = q;
        }
    }

    if (lane == 0) { mlbuf[wv][0] = m2; mlbuf[wv][1] = l; }
    __syncthreads();
    const float M = fmaxf(fmaxf(mlbuf[0][0], mlbuf[1][0]), fmaxf(mlbuf[2][0], mlbuf[3][0]));
    const float wsc = exp2f(m2 - M);
    float L = 0.f;
    #pragma unroll
    for (int w = 0; w < 4; ++w) L += mlbuf[w][1] * exp2f(mlbuf[w][0] - M);
    #pragma unroll
    for (int j = 0; j < 8; ++j)
        *(f32x4*)&obuf[wv][j * 256 + lane * 4] = o4[j] * wsc;
    __syncthreads();

    const int h0 = tid * 8;
    f32x4 s0v = (f32x4){0.f, 0.f, 0.f, 0.f}, s1v = s0v;
    #pragma unroll
    for (int w = 0; w < 4; ++w) {
        s0v += *(const f32x4*)&obuf[w][h0];
        s1v += *(const f32x4*)&obuf[w][h0 + 4];
    }
    float* op = o_part + ((size_t)b * 4 + c) * H + h0;
    *(f32x4*)(op)     = s0v;
    *(f32x4*)(op + 4) = s1v;
    if (tid == 0) {
        ml_part[((size_t)b * 4 + c) * 2]     = M;
        ml_part[((size_t)b * 4 + c) * 2 + 1] = L;
    }
}

// ---------------------------------------------------------------------------
// Combine 4 chunk-partials -> content, written as bf16 hi/lo into A1[:,0:2048]
// ---------------------------------------------------------------------------
__global__ __launch_bounds__(256) void attn_combine(
    const float* __restrict__ o_part,
    const float* __restrict__ ml_part,
    u16* __restrict__ Ah1, u16* __restrict__ Al1)
{
    const int b = blockIdx.x;
    const int tid = threadIdx.x;
    float Mc[4], Lc[4];
    #pragma unroll
    for (int c = 0; c < 4; ++c) {
        Mc[c] = ml_part[((size_t)b * 4 + c) * 2];
        Lc[c] = ml_part[((size_t)b * 4 + c) * 2 + 1];
    }
    const float Mg = fmaxf(fmaxf(Mc[0], Mc[1]), fmaxf(Mc[2], Mc[3]));
    float Lg = 0.f;
    #pragma unroll
    for (int c = 0; c < 4; ++c) Lg += Lc[c] * exp2f(Mc[c] - Mg);
    const float inv = 1.f / Lg;
    const int h0 = tid * 8;
    f32x4 a0 = (f32x4){0.f, 0.f, 0.f, 0.f}, a1 = a0;
    #pragma unroll
    for (int c = 0; c < 4; ++c) {
        const float scl = exp2f(Mc[c] - Mg) * inv;
        const float* op = o_part + ((size_t)b * 4 + c) * H + h0;
        a0 += *(const f32x4*)(op) * scl;
        a1 += *(const f32x4*)(op + 4) * scl;
    }
    u16x8 hh, ll;
    #pragma unroll
    for (int j = 0; j < 4; ++j) { u16 a, l; cvt_hilo(a0[j], a, l); hh[j] = a; ll[j] = l; }
    #pragma unroll
    for (int j = 0; j < 4; ++j) { u16 a, l; cvt_hilo(a1[j], a, l); hh[4+j] = a; ll[4+j] = l; }
    *(u16x8*)(Ah1 + (size_t)b * 4096 + h0) = hh;
    *(u16x8*)(Al1 + (size_t)b * 4096 + h0) = ll;
}

// ---------------------------------------------------------------------------
// Output epilogue: out = tanh(sum of 8 K-partials + attn_b)
// ---------------------------------------------------------------------------
__global__ __launch_bounds__(256) void attn_out(
    const float* __restrict__ part,    // [8][128][2048]
    const float* __restrict__ attn_b,
    float* __restrict__ out)
{
    const int t = blockIdx.x * 256 + threadIdx.x;   // 65536 threads
    const int i = t * 4;
    const int n = i & (H - 1);
    const size_t BH = (size_t)B * H;
    f32x4 s = *(const f32x4*)(attn_b + n);
    #pragma unroll
    for (int p = 0; p < 8; ++p) s += *(const f32x4*)(part + p * BH + i);
    f32x4 r;
    #pragma unroll
    for (int j = 0; j < 4; ++j) r[j] = tanhf(s[j]);
    *(f32x4*)(out + i) = r;
}

// ---------------------------------------------------------------------------
extern "C" void kernel_launch(void* const* d_in, const int* in_sizes, int n_in,
                              void* d_out, int out_size, void* d_ws, size_t ws_size,
                              hipStream_t stream)
{
    const int*   tw     = (const int*)d_in[0];
    const float* hx     = (const float*)d_in[1];
    const float* cx     = (const float*)d_in[2];
    const float* ew     = (const float*)d_in[3];
    const int*   mask   = (const int*)d_in[4];
    const float* embed  = (const float*)d_in[5];
    const float* W_ih   = (const float*)d_in[6];
    const float* W_hh   = (const float*)d_in[7];
    const float* b_ih   = (const float*)d_in[8];
    const float* b_hh   = (const float*)d_in[9];
    const float* attn_W = (const float*)d_in[10];
    const float* attn_b = (const float*)d_in[11];
    float* out = (float*)d_out;

    float* ws      = (float*)d_ws;
    float* gates_p = ws;                                  // 4*128*8192
    float* o_part  = gates_p + 4 * (size_t)B * FOURH;     // 128*4*2048
    float* ml      = o_part + (size_t)B * 4 * H;          // 1024
    float* hxn     = ml + 1024;                           // 128*2048
    float* out_p   = hxn + (size_t)B * H;                 // 8*128*2048
    u16* Ah0 = (u16*)(out_p + 8 * (size_t)B * H);
    u16* Al0 = Ah0 + (size_t)B * 4096;
    u16* Ah1 = Al0 + (size_t)B * 4096;
    u16* Al1 = Ah1 + (size_t)B * 4096;

    gather_convert_A0<<<256, 256, 0, stream>>>(tw, embed, hx, Ah0, Al0);
    split_gemm<0><<<dim3(FOURH / 32, 4), 256, 0, stream>>>(Ah0, Al0, W_ih, W_hh, gates_p);
    lstm_cell<<<256, 256, 0, stream>>>(gates_p, cx, b_ih, b_hh, hxn, Ah1, Al1);
    fused_attn<<<B * 4, 256, 0, stream>>>(hxn, ew, mask, o_part, ml);
    attn_combine<<<B, 256, 0, stream>>>(o_part, ml, Ah1, Al1);
    split_gemm<1><<<dim3(H / 32, 8), 256, 0, stream>>>(Ah1, Al1, attn_W, attn_W, out_p);
    attn_out<<<256, 256, 0, stream>>>(out_p, attn_b, out);
}

// Round 6
// 185.773 us; speedup vs baseline: 3.4034x; 1.1533x over previous
//
#include <hip/hip_runtime.h>
#include <math.h>

#define B 128
#define H 2048
#define S 512
#define FOURH 8192
#define LOG2E 1.4426950408889634f

typedef float  f32x4  __attribute__((ext_vector_type(4)));
typedef short  bf16x8 __attribute__((ext_vector_type(8)));
typedef unsigned short u16;
typedef unsigned short u16x8 __attribute__((ext_vector_type(8)));
typedef unsigned short u16x4 __attribute__((ext_vector_type(4)));

// Split f32 -> bf16 hi + bf16 lo (truncation; lo captures residual, total ~2^-16)
__device__ __forceinline__ void cvt_hilo(float x, u16& h, u16& lo) {
    unsigned int u = __float_as_uint(x);
    h = (u16)(u >> 16);
    float hf = __uint_as_float(u & 0xFFFF0000u);
    float r = x - hf;
    lo = (u16)(__float_as_uint(r) >> 16);
}

// ---------------------------------------------------------------------------
// Kernel 1: build A0 = [embed[tw] | hx] as bf16 hi/lo pair [128][4096]
// ---------------------------------------------------------------------------
__global__ __launch_bounds__(256) void gather_convert_A0(
    const int* __restrict__ tw,
    const float* __restrict__ embed,
    const float* __restrict__ hx,
    u16* __restrict__ Ah, u16* __restrict__ Al)
{
    const int i = (blockIdx.x * 256 + threadIdx.x) * 8;   // over 128*4096
    const int b = i >> 12;
    const int col = i & 4095;
    const float* src = (col < H) ? (embed + (size_t)tw[b] * H + col)
                                 : (hx + (size_t)b * H + (col - H));
    f32x4 v0 = *(const f32x4*)(src);
    f32x4 v1 = *(const f32x4*)(src + 4);
    u16x8 hv, lv;
    #pragma unroll
    for (int j = 0; j < 4; ++j) { u16 h, l; cvt_hilo(v0[j], h, l); hv[j] = h; lv[j] = l; }
    #pragma unroll
    for (int j = 0; j < 4; ++j) { u16 h, l; cvt_hilo(v1[j], h, l); hv[4+j] = h; lv[4+j] = l; }
    *(u16x8*)(Ah + i) = hv;
    *(u16x8*)(Al + i) = lv;
}

// ---------------------------------------------------------------------------
// Split-bf16 MFMA GEMM, 128x128 tile, split-K partials.
// BM=128, BN=128, BK=32, 256 threads = 4 waves in a 2x2 grid; each wave owns
// a 64x64 sub-tile = 4x4 fragments -> 48 MFMA per K-iter per wave against
// 16 ds_read_b128 (3:1) -- 4x better barrier amortization than BN=32.
// 3 MFMA per frag pair: Ah*Wh + Ah*Wl + Al*Wh (err ~2^-16).
// MODE 0: K=4096 split 8 (kz<4 -> W_ih, else W_hh; offset (kz&3)*512);
//         grid (64,8), out [8][128][8192]
// MODE 1: K=4096 split 16 over attn_W [2048][4096]; grid (16,16),
//         out [16][128][2048]
// W prefetch 2-deep (sets X/Y); A prefetch 1-deep (L2-resident).
// ---------------------------------------------------------------------------
template<int MODE>
__global__ __launch_bounds__(256) void split_gemm(
    const u16* __restrict__ Ah, const u16* __restrict__ Al,
    const float* __restrict__ W0, const float* __restrict__ W1,
    float* __restrict__ outp)
{
    constexpr int NOUT = (MODE == 0) ? FOURH : H;
    constexpr int KLEN = (MODE == 0) ? 512 : 256;
    constexpr int NITER = KLEN / 32;       // 16 or 8 (even)
    __shared__ u16 AhS[128][40];
    __shared__ u16 AlS[128][40];
    __shared__ u16 BhS[128][40];
    __shared__ u16 BlS[128][40];

    const int tid = threadIdx.x;
    const int n0 = blockIdx.x * 128;
    const int kz = blockIdx.y;
    const int kbase = kz * KLEN;
    // staging coords: thread -> (row 0..127, 16-col half)
    const int sr = tid >> 1;
    const int sc = (tid & 1) * 16;
    // wave/frag coords
    const int wv = tid >> 6, lane = tid & 63;
    const int wr = (wv >> 1) * 64;         // wave row base
    const int wc = (wv & 1) * 64;          // wave col base
    const int frow = lane & 15, fk = (lane >> 4) * 8, crow = (lane >> 4) * 4;

    const float* Wrow;
    if (MODE == 0)
        Wrow = ((kz < 4) ? W0 : W1) + (size_t)(n0 + sr) * H + (kz & 3) * KLEN + sc;
    else
        Wrow = W0 + (size_t)(n0 + sr) * (2 * H) + kbase + sc;

    const u16* Abase = Ah + (size_t)sr * 4096 + kbase + sc;
    const u16* Lbase = Al + (size_t)sr * 4096 + kbase + sc;

    f32x4 acc[4][4];
    #pragma unroll
    for (int mi = 0; mi < 4; ++mi)
        #pragma unroll
        for (int ni = 0; ni < 4; ++ni)
            acc[mi][ni] = (f32x4){0.f, 0.f, 0.f, 0.f};

    u16x8 rah0, rah1, ral0, ral1;
    auto loadA = [&](int k0) {
        rah0 = *(const u16x8*)(Abase + k0);
        rah1 = *(const u16x8*)(Abase + k0 + 8);
        ral0 = *(const u16x8*)(Lbase + k0);
        ral1 = *(const u16x8*)(Lbase + k0 + 8);
    };
    auto writeA = [&]() {
        *(u16x8*)&AhS[sr][sc]     = rah0;
        *(u16x8*)&AhS[sr][sc + 8] = rah1;
        *(u16x8*)&AlS[sr][sc]     = ral0;
        *(u16x8*)&AlS[sr][sc + 8] = ral1;
    };
    // two named W prefetch sets (rule #20: static names, no runtime indexing)
    f32x4 wX0, wX1, wX2, wX3, wY0, wY1, wY2, wY3;
    auto loadWX = [&](int k0) {
        wX0 = *(const f32x4*)(Wrow + k0);
        wX1 = *(const f32x4*)(Wrow + k0 + 4);
        wX2 = *(const f32x4*)(Wrow + k0 + 8);
        wX3 = *(const f32x4*)(Wrow + k0 + 12);
    };
    auto loadWY = [&](int k0) {
        wY0 = *(const f32x4*)(Wrow + k0);
        wY1 = *(const f32x4*)(Wrow + k0 + 4);
        wY2 = *(const f32x4*)(Wrow + k0 + 8);
        wY3 = *(const f32x4*)(Wrow + k0 + 12);
    };
    auto writeB = [&](const f32x4& b0, const f32x4& b1,
                      const f32x4& b2, const f32x4& b3) {
        u16x8 hv, lv;
        #pragma unroll
        for (int j = 0; j < 4; ++j) { u16 h, l; cvt_hilo(b0[j], h, l); hv[j] = h; lv[j] = l; }
        #pragma unroll
        for (int j = 0; j < 4; ++j) { u16 h, l; cvt_hilo(b1[j], h, l); hv[4+j] = h; lv[4+j] = l; }
        *(u16x8*)&BhS[sr][sc] = hv;
        *(u16x8*)&BlS[sr][sc] = lv;
        #pragma unroll
        for (int j = 0; j < 4; ++j) { u16 h, l; cvt_hilo(b2[j], h, l); hv[j] = h; lv[j] = l; }
        #pragma unroll
        for (int j = 0; j < 4; ++j) { u16 h, l; cvt_hilo(b3[j], h, l); hv[4+j] = h; lv[4+j] = l; }
        *(u16x8*)&BhS[sr][sc + 8] = hv;
        *(u16x8*)&BlS[sr][sc + 8] = lv;
    };
    auto computeTile = [&]() {
        bf16x8 a_h[4], a_l[4], b_h[4], b_l[4];
        #pragma unroll
        for (int mi = 0; mi < 4; ++mi) {
            a_h[mi] = *(const bf16x8*)&AhS[wr + mi * 16 + frow][fk];
            a_l[mi] = *(const bf16x8*)&AlS[wr + mi * 16 + frow][fk];
        }
        #pragma unroll
        for (int ni = 0; ni < 4; ++ni) {
            b_h[ni] = *(const bf16x8*)&BhS[wc + ni * 16 + frow][fk];
            b_l[ni] = *(const bf16x8*)&BlS[wc + ni * 16 + frow][fk];
        }
        #pragma unroll
        for (int mi = 0; mi < 4; ++mi)
            #pragma unroll
            for (int ni = 0; ni < 4; ++ni) {
                acc[mi][ni] = __builtin_amdgcn_mfma_f32_16x16x32_bf16(a_h[mi], b_h[ni], acc[mi][ni], 0, 0, 0);
                acc[mi][ni] = __builtin_amdgcn_mfma_f32_16x16x32_bf16(a_h[mi], b_l[ni], acc[mi][ni], 0, 0, 0);
                acc[mi][ni] = __builtin_amdgcn_mfma_f32_16x16x32_bf16(a_l[mi], b_h[ni], acc[mi][ni], 0, 0, 0);
            }
    };

    loadWX(0);
    loadWY(32);
    loadA(0);

    for (int ks = 0; ks < NITER; ks += 2) {
        // half 1: tile ks (A regs + W set X)
        __syncthreads();
        writeA();
        writeB(wX0, wX1, wX2, wX3);
        __syncthreads();
        loadA((ks + 1) * 32);                     // NITER even: always valid
        if (ks + 2 < NITER) loadWX((ks + 2) * 32);
        computeTile();
        // half 2: tile ks+1 (A regs + W set Y)
        __syncthreads();
        writeA();
        writeB(wY0, wY1, wY2, wY3);
        __syncthreads();
        if (ks + 2 < NITER) loadA((ks + 2) * 32);
        if (ks + 3 < NITER) loadWY((ks + 3) * 32);
        computeTile();
    }

    // C/D layout: col=lane&15, row=(lane>>4)*4+j  [m89/m91]
    #pragma unroll
    for (int mi = 0; mi < 4; ++mi)
        #pragma unroll
        for (int ni = 0; ni < 4; ++ni) {
            const int col = n0 + wc + ni * 16 + frow;
            #pragma unroll
            for (int j = 0; j < 4; ++j) {
                const int row = wr + mi * 16 + crow + j;
                outp[((size_t)kz * B + row) * NOUT + col] = acc[mi][ni][j];
            }
        }
}

// ---------------------------------------------------------------------------
// LSTM cell: sums 8 gate partials + biases, gates, writes hx_new f32 and
// its bf16 hi/lo into the GEMM-1 A buffer (cols 2048..4095).
// ---------------------------------------------------------------------------
__global__ __launch_bounds__(256) void lstm_cell(
    const float* __restrict__ gp,     // [8][128][8192]
    const float* __restrict__ cx,
    const float* __restrict__ b_ih,
    const float* __restrict__ b_hh,
    float* __restrict__ hxn,
    u16* __restrict__ Ah1, u16* __restrict__ Al1)
{
    const int t = blockIdx.x * 256 + threadIdx.x;   // 65536 threads
    const int b = t >> 9;
    const int h = (t & 511) * 4;
    const size_t PS = (size_t)B * FOURH;
    const float* g0 = gp + (size_t)b * FOURH;
    f32x4 gi = *(const f32x4*)(b_ih + h)       + *(const f32x4*)(b_hh + h);
    f32x4 gf = *(const f32x4*)(b_ih + H + h)   + *(const f32x4*)(b_hh + H + h);
    f32x4 gg = *(const f32x4*)(b_ih + 2*H + h) + *(const f32x4*)(b_hh + 2*H + h);
    f32x4 go = *(const f32x4*)(b_ih + 3*H + h) + *(const f32x4*)(b_hh + 3*H + h);
    #pragma unroll
    for (int p = 0; p < 8; ++p) {
        gi += *(const f32x4*)(g0 + p * PS + h);
        gf += *(const f32x4*)(g0 + p * PS + H + h);
        gg += *(const f32x4*)(g0 + p * PS + 2*H + h);
        go += *(const f32x4*)(g0 + p * PS + 3*H + h);
    }
    f32x4 cv = *(const f32x4*)(cx + (size_t)b * H + h);
    f32x4 hv;
    #pragma unroll
    for (int j = 0; j < 4; ++j) {
        float i_ = 1.f / (1.f + expf(-gi[j]));
        float f_ = 1.f / (1.f + expf(-gf[j]));
        float o_ = 1.f / (1.f + expf(-go[j]));
        float g_ = tanhf(gg[j]);
        float c_ = f_ * cv[j] + i_ * g_;
        hv[j] = o_ * tanhf(c_);
    }
    *(f32x4*)(hxn + (size_t)b * H + h) = hv;
    u16x4 hh, ll;
    #pragma unroll
    for (int j = 0; j < 4; ++j) { u16 a, l; cvt_hilo(hv[j], a, l); hh[j] = a; ll[j] = l; }
    *(u16x4*)(Ah1 + (size_t)b * 4096 + H + h) = hh;
    *(u16x4*)(Al1 + (size_t)b * 4096 + H + h) = ll;
}

// ---------------------------------------------------------------------------
// Fused attention: one pass over ew, online softmax in log2 domain.
// Grid: 512 blocks = 128 b x 4 chunks of 128 s. Wave w owns 32 s, processed
// in PAIRS (2 rows/iter): 16 KB in flight, 2 independent dots per softmax
// update. Defer-rescale on the pair max.
// ---------------------------------------------------------------------------
__global__ __launch_bounds__(256) void fused_attn(
    const float* __restrict__ hxn,     // [128][2048]
    const float* __restrict__ ew,      // [512][128][2048]
    const int* __restrict__ mask,      // [512][128]
    float* __restrict__ o_part,        // [128][4][2048] unnormalized
    float* __restrict__ ml_part)       // [128][4][2] = (M2, L) log2-domain
{
    __shared__ float mlbuf[4][2];
    __shared__ float obuf[4][2048];

    const int tid = threadIdx.x;
    const int b = blockIdx.x >> 2;
    const int c = blockIdx.x & 3;
    const int wv = tid >> 6;
    const int lane = tid & 63;
    const int s0 = c * 128 + wv * 32;

    // mask bits for this wave's 32 s-values
    unsigned long long mbits;
    {
        int mv = (lane < 32) ? mask[(s0 + lane) * B + b] : 0;
        mbits = __ballot(mv != 0);
    }

    f32x4 hxv[8];
    const float* hp = hxn + (size_t)b * H + lane * 4;
    #pragma unroll
    for (int j = 0; j < 8; ++j) hxv[j] = *(const f32x4*)(hp + j * 256);

    f32x4 o4[8];
    #pragma unroll
    for (int j = 0; j < 8; ++j) o4[j] = (f32x4){0.f, 0.f, 0.f, 0.f};
    float m2 = -3.0e38f, l = 0.f;

    const size_t SSTRIDE = (size_t)B * H;
    const float* rowp = ew + ((size_t)s0 * B + b) * H + lane * 4;

    f32x4 eva[8], evb[8];
    #pragma unroll
    for (int j = 0; j < 8; ++j) eva[j] = *(const f32x4*)(rowp + j * 256);
    #pragma unroll
    for (int j = 0; j < 8; ++j) evb[j] = *(const f32x4*)(rowp + SSTRIDE + j * 256);

    for (int pi = 0; pi < 16; ++pi) {
        f32x4 ca[8], cb[8];
        #pragma unroll
        for (int j = 0; j < 8; ++j) { ca[j] = eva[j]; cb[j] = evb[j]; }
        if (pi < 15) {
            const float* na = rowp + (size_t)(2 * pi + 2) * SSTRIDE;
            const float* nb = rowp + (size_t)(2 * pi + 3) * SSTRIDE;
            #pragma unroll
            for (int j = 0; j < 8; ++j) eva[j] = *(const f32x4*)(na + j * 256);
            #pragma unroll
            for (int j = 0; j < 8; ++j) evb[j] = *(const f32x4*)(nb + j * 256);
        }
        float pa = 0.f, pb = 0.f;
        #pragma unroll
        for (int j = 0; j < 8; ++j) {
            f32x4 ta = ca[j] * hxv[j];
            f32x4 tb = cb[j] * hxv[j];
            pa += ta[0] + ta[1] + ta[2] + ta[3];
            pb += tb[0] + tb[1] + tb[2] + tb[3];
        }
        #pragma unroll
        for (int off = 32; off; off >>= 1) {
            pa += __shfl_xor(pa, off, 64);
            pb += __shfl_xor(pb, off, 64);
        }
        const float p2a = ((mbits >> (2 * pi)) & 1) ? pa * LOG2E : -1.5e9f;
        const float p2b = ((mbits >> (2 * pi + 1)) & 1) ? pb * LOG2E : -1.5e9f;
        const float q = fmaxf(p2a, p2b);
        if (q <= m2) {
            // common path: no new max, no o4 rescale
            const float ea = exp2f(p2a - m2);
            const float eb = exp2f(p2b - m2);
            l += ea + eb;
            #pragma unroll
            for (int j = 0; j < 8; ++j) o4[j] += ca[j] * ea + cb[j] * eb;
        } else {
            const float sc = exp2f(m2 - q);
            const float ea = exp2f(p2a - q);
            const float eb = exp2f(p2b - q);
            l = l * sc + ea + eb;
            #pragma unroll
            for (int j = 0; j < 8; ++j) o4[j] = o4[j] * sc + ca[j] * ea + cb[j] * eb;
            m2 = q;
        }
    }

    if (lane == 0) { mlbuf[wv][0] = m2; mlbuf[wv][1] = l; }
    __syncthreads();
    const float M = fmaxf(fmaxf(mlbuf[0][0], mlbuf[1][0]), fmaxf(mlbuf[2][0], mlbuf[3][0]));
    const float wsc = exp2f(m2 - M);
    float L = 0.f;
    #pragma unroll
    for (int w = 0; w < 4; ++w) L += mlbuf[w][1] * exp2f(mlbuf[w][0] - M);
    #pragma unroll
    for (int j = 0; j < 8; ++j)
        *(f32x4*)&obuf[wv][j * 256 + lane * 4] = o4[j] * wsc;
    __syncthreads();

    const int h0 = tid * 8;
    f32x4 s0v = (f32x4){0.f, 0.f, 0.f, 0.f}, s1v = s0v;
    #pragma unroll
    for (int w = 0; w < 4; ++w) {
        s0v += *(const f32x4*)&obuf[w][h0];
        s1v += *(const f32x4*)&obuf[w][h0 + 4];
    }
    float* op = o_part + ((size_t)b * 4 + c) * H + h0;
    *(f32x4*)(op)     = s0v;
    *(f32x4*)(op + 4) = s1v;
    if (tid == 0) {
        ml_part[((size_t)b * 4 + c) * 2]     = M;
        ml_part[((size_t)b * 4 + c) * 2 + 1] = L;
    }
}

// ---------------------------------------------------------------------------
// Combine 4 chunk-partials -> content, written as bf16 hi/lo into A1[:,0:2048]
// ---------------------------------------------------------------------------
__global__ __launch_bounds__(256) void attn_combine(
    const float* __restrict__ o_part,
    const float* __restrict__ ml_part,
    u16* __restrict__ Ah1, u16* __restrict__ Al1)
{
    const int b = blockIdx.x;
    const int tid = threadIdx.x;
    float Mc[4], Lc[4];
    #pragma unroll
    for (int c = 0; c < 4; ++c) {
        Mc[c] = ml_part[((size_t)b * 4 + c) * 2];
        Lc[c] = ml_part[((size_t)b * 4 + c) * 2 + 1];
    }
    const float Mg = fmaxf(fmaxf(Mc[0], Mc[1]), fmaxf(Mc[2], Mc[3]));
    float Lg = 0.f;
    #pragma unroll
    for (int c = 0; c < 4; ++c) Lg += Lc[c] * exp2f(Mc[c] - Mg);
    const float inv = 1.f / Lg;
    const int h0 = tid * 8;
    f32x4 a0 = (f32x4){0.f, 0.f, 0.f, 0.f}, a1 = a0;
    #pragma unroll
    for (int c = 0; c < 4; ++c) {
        const float scl = exp2f(Mc[c] - Mg) * inv;
        const float* op = o_part + ((size_t)b * 4 + c) * H + h0;
        a0 += *(const f32x4*)(op) * scl;
        a1 += *(const f32x4*)(op + 4) * scl;
    }
    u16x8 hh, ll;
    #pragma unroll
    for (int j = 0; j < 4; ++j) { u16 a, l; cvt_hilo(a0[j], a, l); hh[j] = a; ll[j] = l; }
    #pragma unroll
    for (int j = 0; j < 4; ++j) { u16 a, l; cvt_hilo(a1[j], a, l); hh[4+j] = a; ll[4+j] = l; }
    *(u16x8*)(Ah1 + (size_t)b * 4096 + h0) = hh;
    *(u16x8*)(Al1 + (size_t)b * 4096 + h0) = ll;
}

// ---------------------------------------------------------------------------
// Output epilogue: out = tanh(sum of 16 K-partials + attn_b)
// ---------------------------------------------------------------------------
__global__ __launch_bounds__(256) void attn_out(
    const float* __restrict__ part,    // [16][128][2048]
    const float* __restrict__ attn_b,
    float* __restrict__ out)
{
    const int t = blockIdx.x * 256 + threadIdx.x;   // 65536 threads
    const int i = t * 4;
    const int n = i & (H - 1);
    const size_t BH = (size_t)B * H;
    f32x4 s = *(const f32x4*)(attn_b + n);
    #pragma unroll
    for (int p = 0; p < 16; ++p) s += *(const f32x4*)(part + p * BH + i);
    f32x4 r;
    #pragma unroll
    for (int j = 0; j < 4; ++j) r[j] = tanhf(s[j]);
    *(f32x4*)(out + i) = r;
}

// ---------------------------------------------------------------------------
extern "C" void kernel_launch(void* const* d_in, const int* in_sizes, int n_in,
                              void* d_out, int out_size, void* d_ws, size_t ws_size,
                              hipStream_t stream)
{
    const int*   tw     = (const int*)d_in[0];
    const float* hx     = (const float*)d_in[1];
    const float* cx     = (const float*)d_in[2];
    const float* ew     = (const float*)d_in[3];
    const int*   mask   = (const int*)d_in[4];
    const float* embed  = (const float*)d_in[5];
    const float* W_ih   = (const float*)d_in[6];
    const float* W_hh   = (const float*)d_in[7];
    const float* b_ih   = (const float*)d_in[8];
    const float* b_hh   = (const float*)d_in[9];
    const float* attn_W = (const float*)d_in[10];
    const float* attn_b = (const float*)d_in[11];
    float* out = (float*)d_out;

    float* ws      = (float*)d_ws;
    float* gates_p = ws;                                  // 8*128*8192
    float* o_part  = gates_p + 8 * (size_t)B * FOURH;     // 128*4*2048
    float* ml      = o_part + (size_t)B * 4 * H;          // 1024
    float* hxn     = ml + 1024;                           // 128*2048
    float* out_p   = hxn + (size_t)B * H;                 // 16*128*2048
    u16* Ah0 = (u16*)(out_p + 16 * (size_t)B * H);
    u16* Al0 = Ah0 + (size_t)B * 4096;
    u16* Ah1 = Al0 + (size_t)B * 4096;
    u16* Al1 = Ah1 + (size_t)B * 4096;

    gather_convert_A0<<<256, 256, 0, stream>>>(tw, embed, hx, Ah0, Al0);
    split_gemm<0><<<dim3(FOURH / 128, 8), 256, 0, stream>>>(Ah0, Al0, W_ih, W_hh, gates_p);
    lstm_cell<<<256, 256, 0, stream>>>(gates_p, cx, b_ih, b_hh, hxn, Ah1, Al1);
    fused_attn<<<B * 4, 256, 0, stream>>>(hxn, ew, mask, o_part, ml);
    attn_combine<<<B, 256, 0, stream>>>(o_part, ml, Ah1, Al1);
    split_gemm<1><<<dim3(H / 128, 16), 256, 0, stream>>>(Ah1, Al1, attn_W, attn_W, out_p);
    attn_out<<<256, 256, 0, stream>>>(out_p, attn_b, out);
}